// Round 4
// baseline (3449.743 us; speedup 1.0000x reference)
//
#include <hip/hip_runtime.h>
#include <hip/hip_bf16.h>

typedef __hip_bfloat16 bf16;

#define TT 64
#define NN_ 1024
#define PP 256
#define HH 256
#define EE 512
#define SS 16
#define RR 16

__device__ __forceinline__ float toF(float v) { return v; }
__device__ __forceinline__ float toF(bf16 v) { return __bfloat162float(v); }
__device__ __forceinline__ bf16 f2b(float v) { return __float2bfloat16(v); }

enum { EPI_F32 = 0, EPI_SIG_F32 = 1, EPI_RELU_F32 = 2, EPI_BF16 = 3, EPI_SPLIT_SILU = 4, EPI_OUT = 5 };

// fp32-accumulate tiled GEMM: C[M,Nn] = A[M,K] @ B[K,Nn] (+epilogue)
// BM=BN=64, BK=16, 256 threads, 4x4 micro-tile.
// CAT: A row = [A[row & rowmask, 0:256] | A2[row, 0:256]] (K = 512)
// TRANSB: B stored [Nn,K] row-major.
template <typename TA, typename TA2, typename TB, bool TRANSB, bool CAT, int EPI>
__global__ __launch_bounds__(256) void gemm_k(
    const TA* __restrict__ A, const TA2* __restrict__ A2, unsigned rowmask,
    const TB* __restrict__ B,
    float* __restrict__ outF, bf16* __restrict__ outB, bf16* __restrict__ outB2,
    const float* __restrict__ bias, const bf16* __restrict__ resid,
    const float* __restrict__ sbeta, float alpha,
    int M, int Nn, int K, int lda, int ldb)
{
    __shared__ float As[16][68];
    __shared__ float Bs[16][68];
    const int tid = threadIdx.x;
    const int tx = tid & 15, ty = tid >> 4;
    const int m0 = blockIdx.x * 64, n0 = blockIdx.y * 64;
    float acc[4][4] = {};

    for (int k0 = 0; k0 < K; k0 += 16) {
        { // stage A tile: 64 rows x 16 k
            int row = tid >> 2;
            int kk0 = (tid & 3) * 4;
            int grow = m0 + row;
#pragma unroll
            for (int j = 0; j < 4; j++) {
                int kk = kk0 + j, gk = k0 + kk;
                float v = 0.f;
                if (grow < M) {
                    if (!CAT) {
                        v = toF(A[(size_t)grow * lda + gk]);
                    } else {
                        if (gk < 256) v = toF(A[(size_t)(grow & rowmask) * 256 + gk]);
                        else          v = toF(A2[(size_t)grow * 256 + (gk - 256)]);
                    }
                }
                As[kk][row] = v;
            }
        }
        if (!TRANSB) {
            int kk = tid >> 4;
            int c0 = (tid & 15) * 4;
#pragma unroll
            for (int j = 0; j < 4; j++) {
                int col = c0 + j, gn = n0 + col;
                Bs[kk][col] = (gn < Nn) ? toF(B[(size_t)(k0 + kk) * ldb + gn]) : 0.f;
            }
        } else {
            int col = tid >> 2;
            int kk0 = (tid & 3) * 4;
            int gn = n0 + col;
#pragma unroll
            for (int j = 0; j < 4; j++) {
                int kk = kk0 + j;
                Bs[kk][col] = (gn < Nn) ? toF(B[(size_t)gn * ldb + (k0 + kk)]) : 0.f;
            }
        }
        __syncthreads();
#pragma unroll
        for (int kk = 0; kk < 16; kk++) {
            float a[4], b[4];
#pragma unroll
            for (int i = 0; i < 4; i++) a[i] = As[kk][ty * 4 + i];
#pragma unroll
            for (int j = 0; j < 4; j++) b[j] = Bs[kk][tx * 4 + j];
#pragma unroll
            for (int i = 0; i < 4; i++)
#pragma unroll
                for (int j = 0; j < 4; j++)
                    acc[i][j] = fmaf(a[i], b[j], acc[i][j]);
        }
        __syncthreads();
    }

    float gb = 0.f;
    if (EPI == EPI_SIG_F32 && sbeta) gb = sbeta[0];
#pragma unroll
    for (int i = 0; i < 4; i++) {
        int row = m0 + ty * 4 + i;
        if (row >= M) continue;
#pragma unroll
        for (int j = 0; j < 4; j++) {
            int col = n0 + tx * 4 + j;
            if (col >= Nn) continue;
            float v = acc[i][j];
            if (EPI == EPI_F32) {
                if (bias) v += bias[col];
                outF[(size_t)row * Nn + col] = v;
            } else if (EPI == EPI_SIG_F32) {
                v = v * alpha + gb;
                outF[(size_t)row * Nn + col] = 1.f / (1.f + __expf(-v));
            } else if (EPI == EPI_RELU_F32) {
                v += bias[col];
                outF[(size_t)row * Nn + col] = fmaxf(v, 0.f);
            } else if (EPI == EPI_BF16) {
                v += bias[col];
                outB[(size_t)row * Nn + col] = f2b(v);
            } else if (EPI == EPI_SPLIT_SILU) {
                v += bias[col];
                float s = v / (1.f + __expf(-v));
                if (col < EE) outB[(size_t)row * EE + col] = f2b(s);
                else          outB2[(size_t)row * EE + (col - EE)] = f2b(s);
            } else if (EPI == EPI_OUT) {
                v += bias[col];
                v += toF(resid[(size_t)row * 256 + col]);
                int t = row & 63, n = row >> 6;
                outF[((size_t)t * NN_ + n) * 256 + col] = v;   // f32 OUTPUT
            }
        }
    }
}

// Sparse aggregation: out[t,n,:] = sum_j adj[t,n,j] * (gate?) * src[j,:]
// One wave per (t,n) row; ballot over nonzero adj entries.
template <bool GATED>
__global__ __launch_bounds__(256) void agg_k(
    const float* __restrict__ adj, const float* __restrict__ gates,
    const void* __restrict__ src_, bf16* __restrict__ out)
{
    int w = blockIdx.x * 4 + (threadIdx.x >> 6);
    int lane = threadIdx.x & 63;
    int t = w >> 10, n = w & 1023;
    const float* adjrow = adj + ((size_t)t * NN_ + n) * NN_;
    const float* srcF = (const float*)src_;
    const bf16* srcB = (const bf16*)src_;
    float a0 = 0.f, a1 = 0.f, a2 = 0.f, a3 = 0.f;
    for (int ch = 0; ch < 16; ch++) {
        int j0 = ch * 64;
        float av = adjrow[j0 + lane];
        unsigned long long m = __ballot(av != 0.f);
        while (m) {
            int l = __builtin_ctzll(m);
            m &= (m - 1);
            int j = j0 + l;
            float wgt = __shfl(av, l, 64);
            if (GATED) {
                wgt *= gates[(size_t)n * NN_ + j];
                const float* r = srcF + (size_t)j * 256;
                a0 = fmaf(wgt, r[lane], a0);
                a1 = fmaf(wgt, r[lane + 64], a1);
                a2 = fmaf(wgt, r[lane + 128], a2);
                a3 = fmaf(wgt, r[lane + 192], a3);
            } else {
                const bf16* r = srcB + ((size_t)t * NN_ + j) * 256;
                a0 = fmaf(wgt, toF(r[lane]), a0);
                a1 = fmaf(wgt, toF(r[lane + 64]), a1);
                a2 = fmaf(wgt, toF(r[lane + 128]), a2);
                a3 = fmaf(wgt, toF(r[lane + 192]), a3);
            }
        }
    }
    bf16* o = out + ((size_t)t * NN_ + n) * 256;
    o[lane] = f2b(a0);
    o[lane + 64] = f2b(a1);
    o[lane + 128] = f2b(a2);
    o[lane + 192] = f2b(a3);
}

// Two-pass LayerNorm over 256 cols; one block per row.
// TRANSOUT: input rows r = t*1024+n -> output rows n*64+t.
template <typename TI, bool TRANSOUT>
__global__ __launch_bounds__(256) void ln_k(
    const TI* __restrict__ X, const float* __restrict__ g, const float* __restrict__ b,
    bf16* __restrict__ out)
{
    int r = blockIdx.x, c = threadIdx.x;
    int wid = c >> 6;
    __shared__ float w1[4], w2[4];
    float x = toF(X[(size_t)r * 256 + c]);
    float s = x;
#pragma unroll
    for (int o = 1; o < 64; o <<= 1) s += __shfl_xor(s, o, 64);
    if ((c & 63) == 0) w1[wid] = s;
    __syncthreads();
    float mu = (w1[0] + w1[1] + w1[2] + w1[3]) * (1.f / 256.f);
    float d = x - mu;
    float s2 = d * d;
#pragma unroll
    for (int o = 1; o < 64; o <<= 1) s2 += __shfl_xor(s2, o, 64);
    if ((c & 63) == 0) w2[wid] = s2;
    __syncthreads();
    float var = (w2[0] + w2[1] + w2[2] + w2[3]) * (1.f / 256.f);
    float inv = rsqrtf(fmaxf(var, 0.f) + 1e-5f);
    float y = d * inv * g[c] + b[c];
    int orow = TRANSOUT ? ((r & 1023) * 64 + (r >> 10)) : r;
    out[(size_t)orow * 256 + c] = f2b(y);
}

// Mamba selective scan: one thread per (n,e); h[16] in registers; T=64 steps.
__global__ __launch_bounds__(256) void scan_k(
    const bf16* __restrict__ u, const bf16* __restrict__ sg,
    const float* __restrict__ d1, const float* __restrict__ Bm, const float* __restrict__ Cm,
    const float* __restrict__ Wdt, const float* __restrict__ bdt,
    const float* __restrict__ Alog, const float* __restrict__ D,
    bf16* __restrict__ yg)
{
    int gid = blockIdx.x * 256 + threadIdx.x;
    int n = gid >> 9, e = gid & 511;
    float a[16], wdt[16], h[16];
#pragma unroll
    for (int s = 0; s < 16; s++) {
        a[s] = -__expf(Alog[e * 16 + s]);
        h[s] = 0.f;
    }
#pragma unroll
    for (int k = 0; k < 16; k++) wdt[k] = Wdt[(size_t)k * EE + e];
    float bdte = bdt[e], De = D[e];
    for (int t = 0; t < TT; t++) {
        size_t r = (size_t)n * TT + t;
        float acc = bdte;
#pragma unroll
        for (int k = 0; k < 16; k++) acc = fmaf(d1[r * 16 + k], wdt[k], acc);
        float delta = (acc > 20.f) ? acc : log1pf(__expf(acc));
        float uv = toF(u[r * EE + e]);
        float du = delta * uv;
        float y = 0.f;
#pragma unroll
        for (int s = 0; s < 16; s++) {
            float ad = __expf(delta * a[s]);
            h[s] = fmaf(ad, h[s], du * Bm[r * 16 + s]);
            y = fmaf(Cm[r * 16 + s], h[s], y);
        }
        float o = (y + uv * De) * toF(sg[r * EE + e]);
        yg[r * EE + e] = f2b(o);
    }
}

extern "C" void kernel_launch(void* const* d_in, const int* in_sizes, int n_in,
                              void* d_out, int out_size, void* d_ws, size_t ws_size,
                              hipStream_t stream)
{
    const float* adj   = (const float*)d_in[0];
    const float* pos   = (const float*)d_in[1];
    const float* g1Wm  = (const float*)d_in[2];
    const float* g1bm  = (const float*)d_in[3];
    const float* g1Wq  = (const float*)d_in[4];
    const float* g1Wk  = (const float*)d_in[5];
    const float* g1gb  = (const float*)d_in[6];
    const float* g1Wu  = (const float*)d_in[7];
    const float* g1bu  = (const float*)d_in[8];
    const float* g1lg  = (const float*)d_in[9];
    const float* g1lb  = (const float*)d_in[10];
    const float* g2Wm  = (const float*)d_in[11];
    const float* g2bm  = (const float*)d_in[12];
    const float* g2Wu  = (const float*)d_in[13];
    const float* g2bu  = (const float*)d_in[14];
    const float* g2lg  = (const float*)d_in[15];
    const float* g2lb  = (const float*)d_in[16];
    const float* mlg   = (const float*)d_in[17];
    const float* mlb   = (const float*)d_in[18];
    const float* mWin  = (const float*)d_in[19];
    const float* mbin  = (const float*)d_in[20];
    const float* mWd   = (const float*)d_in[21];
    const float* mbd   = (const float*)d_in[22];
    const float* mWdt  = (const float*)d_in[23];
    const float* mbdt  = (const float*)d_in[24];
    const float* mWB   = (const float*)d_in[25];
    const float* mbB   = (const float*)d_in[26];
    const float* mWC   = (const float*)d_in[27];
    const float* mbC   = (const float*)d_in[28];
    const float* mAlog = (const float*)d_in[29];
    const float* mD    = (const float*)d_in[30];
    const float* mWout = (const float*)d_in[31];
    const float* mbout = (const float*)d_in[32];
    float* out = (float*)d_out;                      // f32 OUTPUT
    char* ws = (char*)d_ws;

    const size_t BIGE = (size_t)TT * NN_ * 256;
    size_t o = 0;
    auto alloc = [&](size_t bytes) { size_t r = o; o += (bytes + 255) & ~(size_t)255; return r; };

    float* msgs  = (float*)(ws + alloc((size_t)NN_ * 256 * 4));
    float* q     = (float*)(ws + alloc((size_t)NN_ * 256 * 4));
    float* kk    = (float*)(ws + alloc((size_t)NN_ * 256 * 4));
    float* gates = (float*)(ws + alloc((size_t)NN_ * NN_ * 4));
    bf16*  Ra    = (bf16*)(ws + alloc(BIGE * 2));                 // agg / msgs2 / xn
    size_t off_x1 = alloc(BIGE * 2);
    bf16*  x1    = (bf16*)(ws + off_x1);
    bf16*  agg2  = (bf16*)(ws + alloc(BIGE * 2));
    bf16*  x2    = (bf16*)(ws + alloc(BIGE * 2));                 // res, [N,T,H]
    size_t off_t0 = alloc(BIGE * 4);
    float* t0    = (float*)(ws + off_t0);
    bf16*  sg    = (bf16*)(ws + alloc((size_t)NN_ * TT * EE * 2));
    float* d1    = (float*)(ws + alloc((size_t)NN_ * TT * RR * 4));
    float* Bm    = (float*)(ws + alloc((size_t)NN_ * TT * SS * 4));
    float* Cm    = (float*)(ws + alloc((size_t)NN_ * TT * SS * 4));
    bf16*  u     = (bf16*)(ws + off_x1);                          // aliases x1+agg2
    bf16*  yg    = (bf16*)(ws + off_t0);                          // aliases t0

    const unsigned ALLR = 0xFFFFFFFFu;
    const int M = TT * NN_;

    // S0: msgs = pos @ g1_Wm + bm (f32)
    gemm_k<float, float, float, false, false, EPI_F32><<<dim3(16, 4), 256, 0, stream>>>(
        pos, pos, ALLR, g1Wm, msgs, nullptr, nullptr, g1bm, nullptr, nullptr, 1.f,
        NN_, 256, 256, 256, 256);
    // S1: q = msgs @ Wq ; k = msgs @ Wk
    gemm_k<float, float, float, false, false, EPI_F32><<<dim3(16, 4), 256, 0, stream>>>(
        msgs, msgs, ALLR, g1Wq, q, nullptr, nullptr, nullptr, nullptr, nullptr, 1.f,
        NN_, 256, 256, 256, 256);
    gemm_k<float, float, float, false, false, EPI_F32><<<dim3(16, 4), 256, 0, stream>>>(
        msgs, msgs, ALLR, g1Wk, kk, nullptr, nullptr, nullptr, nullptr, nullptr, 1.f,
        NN_, 256, 256, 256, 256);
    // S2: gates = sigmoid(q @ k^T / 16 + gb)
    gemm_k<float, float, float, true, false, EPI_SIG_F32><<<dim3(16, 16), 256, 0, stream>>>(
        q, q, ALLR, kk, gates, nullptr, nullptr, nullptr, nullptr, g1gb, 1.f / 16.f,
        NN_, NN_, 256, 256, 256);
    // S3: agg -> Ra (bf16)
    agg_k<true><<<TT * NN_ / 4, 256, 0, stream>>>(adj, gates, msgs, Ra);
    // S4: t0 = relu(cat(pos, agg) @ g1_Wu + bu)
    gemm_k<float, bf16, float, false, true, EPI_RELU_F32><<<dim3(1024, 4), 256, 0, stream>>>(
        pos, Ra, 1023u, g1Wu, t0, nullptr, nullptr, g1bu, nullptr, nullptr, 1.f,
        M, 256, 512, 256, 256);
    // S5: x1 = LN(t0)
    ln_k<float, false><<<M, 256, 0, stream>>>(t0, g1lg, g1lb, x1);
    // S6: msgs2 = x1 @ g2_Wm + bm -> Ra (bf16)
    gemm_k<bf16, bf16, float, false, false, EPI_BF16><<<dim3(1024, 4), 256, 0, stream>>>(
        x1, x1, ALLR, g2Wm, nullptr, Ra, nullptr, g2bm, nullptr, nullptr, 1.f,
        M, 256, 256, 256, 256);
    // S7: agg2 = adj @ msgs2
    agg_k<false><<<TT * NN_ / 4, 256, 0, stream>>>(adj, nullptr, Ra, agg2);
    // S8: t0 = relu(cat(x1, agg2) @ g2_Wu + bu)
    gemm_k<bf16, bf16, float, false, true, EPI_RELU_F32><<<dim3(1024, 4), 256, 0, stream>>>(
        x1, agg2, ALLR, g2Wu, t0, nullptr, nullptr, g2bu, nullptr, nullptr, 1.f,
        M, 256, 512, 256, 256);
    // S9: x2 = LN(t0), transposed to [N,T,H]
    ln_k<float, true><<<M, 256, 0, stream>>>(t0, g2lg, g2lb, x2);
    // S10: xn = LN(x2) -> Ra
    ln_k<bf16, false><<<M, 256, 0, stream>>>(x2, mlg, mlb, Ra);
    // S11: xp = xn @ m_Win + bin; u / sg = silu halves
    gemm_k<bf16, bf16, float, false, false, EPI_SPLIT_SILU><<<dim3(1024, 16), 256, 0, stream>>>(
        Ra, Ra, ALLR, mWin, nullptr, u, sg, mbin, nullptr, nullptr, 1.f,
        M, 1024, 256, 256, 1024);
    // S12: d1 / Bm / Cm (f32 [M,16])
    gemm_k<bf16, bf16, float, false, false, EPI_F32><<<dim3(1024, 1), 256, 0, stream>>>(
        u, u, ALLR, mWd, d1, nullptr, nullptr, mbd, nullptr, nullptr, 1.f,
        M, 16, 512, 512, 16);
    gemm_k<bf16, bf16, float, false, false, EPI_F32><<<dim3(1024, 1), 256, 0, stream>>>(
        u, u, ALLR, mWB, Bm, nullptr, nullptr, mbB, nullptr, nullptr, 1.f,
        M, 16, 512, 512, 16);
    gemm_k<bf16, bf16, float, false, false, EPI_F32><<<dim3(1024, 1), 256, 0, stream>>>(
        u, u, ALLR, mWC, Cm, nullptr, nullptr, mbC, nullptr, nullptr, 1.f,
        M, 16, 512, 512, 16);
    // S13: selective scan -> yg (bf16)
    scan_k<<<NN_ * EE / 256, 256, 0, stream>>>(u, sg, d1, Bm, Cm, mWdt, mbdt, mAlog, mD, yg);
    // S14: out = yg @ m_Wout + bout + res -> [T,N,H] f32
    gemm_k<bf16, bf16, float, false, false, EPI_OUT><<<dim3(1024, 4), 256, 0, stream>>>(
        yg, yg, ALLR, mWout, out, nullptr, nullptr, mbout, x2, nullptr, 1.f,
        M, 256, 512, 512, 256);

    (void)in_sizes; (void)n_in; (void)out_size; (void)ws_size;
}

// Round 6
// 1576.907 us; speedup vs baseline: 2.1877x; 2.1877x over previous
//
#include <hip/hip_runtime.h>
#include <hip/hip_bf16.h>

typedef __hip_bfloat16 bf16;
typedef __attribute__((ext_vector_type(8))) short s16x8;
typedef __attribute__((ext_vector_type(4))) short s16x4;
typedef __attribute__((ext_vector_type(4))) float f32x4;

#define TT 64
#define NN_ 1024
#define EE 512

__device__ __forceinline__ float toF(float v) { return v; }
__device__ __forceinline__ float toF(bf16 v) { return __bfloat162float(v); }
__device__ __forceinline__ bf16 f2b(float v) { return __float2bfloat16(v); }

enum { EPI_F32 = 0, EPI_SIG_F32 = 1 };
enum { E_LN1 = 0, E_BF16 = 1, E_LN2 = 2, E_SILU = 3, E_OUT = 4, E_TRI = 5 };

// ---------------- small fp32 tiled GEMM (S0-S2 only; 1024-row problems) -------------
template <bool TRANSB, int EPI>
__global__ __launch_bounds__(256) void gemm_k(
    const float* __restrict__ A, const float* __restrict__ B,
    float* __restrict__ outF, const float* __restrict__ bias,
    const float* __restrict__ sbeta, float alpha,
    int M, int Nn, int K, int lda, int ldb)
{
    __shared__ float As[16][68];
    __shared__ float Bs[16][68];
    const int tid = threadIdx.x;
    const int tx = tid & 15, ty = tid >> 4;
    const int m0 = blockIdx.x * 64, n0 = blockIdx.y * 64;
    float acc[4][4] = {};

    for (int k0 = 0; k0 < K; k0 += 16) {
        {
            int row = tid >> 2, kk0 = (tid & 3) * 4, grow = m0 + row;
#pragma unroll
            for (int j = 0; j < 4; j++) {
                int kk = kk0 + j, gk = k0 + kk;
                As[kk][row] = (grow < M) ? A[(size_t)grow * lda + gk] : 0.f;
            }
        }
        if (!TRANSB) {
            int kk = tid >> 4, c0 = (tid & 15) * 4;
#pragma unroll
            for (int j = 0; j < 4; j++) {
                int col = c0 + j, gn = n0 + col;
                Bs[kk][col] = (gn < Nn) ? B[(size_t)(k0 + kk) * ldb + gn] : 0.f;
            }
        } else {
            int col = tid >> 2, kk0 = (tid & 3) * 4, gn = n0 + col;
#pragma unroll
            for (int j = 0; j < 4; j++) {
                int kk = kk0 + j;
                Bs[kk][col] = (gn < Nn) ? B[(size_t)gn * ldb + (k0 + kk)] : 0.f;
            }
        }
        __syncthreads();
#pragma unroll
        for (int kk = 0; kk < 16; kk++) {
            float a[4], b[4];
#pragma unroll
            for (int i = 0; i < 4; i++) a[i] = As[kk][ty * 4 + i];
#pragma unroll
            for (int j = 0; j < 4; j++) b[j] = Bs[kk][tx * 4 + j];
#pragma unroll
            for (int i = 0; i < 4; i++)
#pragma unroll
                for (int j = 0; j < 4; j++)
                    acc[i][j] = fmaf(a[i], b[j], acc[i][j]);
        }
        __syncthreads();
    }

    float gb = (EPI == EPI_SIG_F32 && sbeta) ? sbeta[0] : 0.f;
#pragma unroll
    for (int i = 0; i < 4; i++) {
        int row = m0 + ty * 4 + i;
        if (row >= M) continue;
#pragma unroll
        for (int j = 0; j < 4; j++) {
            int col = n0 + tx * 4 + j;
            if (col >= Nn) continue;
            float v = acc[i][j];
            if (EPI == EPI_F32) {
                if (bias) v += bias[col];
                outF[(size_t)row * Nn + col] = v;
            } else {
                v = v * alpha + gb;
                outF[(size_t)row * Nn + col] = 1.f / (1.f + __expf(-v));
            }
        }
    }
}

// ---------------- MFMA bf16 GEMM -----------------------------------------------------
// C[M,Nn] = A[M,K](bf16) @ BT[Nn,K]^T(bf16), fp32 accum, fused epilogues.
// 256 threads = 4 waves. BK=32. BN=256: waves side-by-side (wave=64 cols);
// BM=256/BN=64: waves stacked on M. Each wave computes 64x64 via 4x4 mfma_16x16x32.
// CAT: A row r = [A1[(r&rowmask),0:256] | A2[r,0:256]], K=512.
template <int BM, int BN, bool CAT, int EPI>
__global__ __launch_bounds__(256) void mfma_k(
    const bf16* __restrict__ A1, const bf16* __restrict__ A2, unsigned rowmask,
    const bf16* __restrict__ BT, const float* __restrict__ bias,
    float* __restrict__ outF, float* __restrict__ outF2, float* __restrict__ outF3,
    bf16* __restrict__ outB, bf16* __restrict__ outB2,
    const float* __restrict__ g1, const float* __restrict__ b1,
    const float* __restrict__ g2, const float* __restrict__ b2,
    const bf16* __restrict__ resid,
    int M, int K)
{
    constexpr bool LN = (EPI == E_LN1 || EPI == E_LN2);
    constexpr int STAGE_B = (BM * 32 + BN * 32) * 2;
    constexpr int SB = LN ? (64 * 260 * 4) : STAGE_B;
    __shared__ __align__(16) char smem[SB];
    short* As = (short*)smem;
    short* Bs = As + BM * 32;
    float* Cs = (float*)smem;   // LN epilogue reuses staging LDS

    const int tid = threadIdx.x;
    const int wid = tid >> 6, lane = tid & 63;
    const int wr = (BN == 256) ? 0 : wid;     // wave 64-row block
    const int wc = (BN == 256) ? wid : 0;     // wave 64-col block
    const int m0 = blockIdx.x * BM, n0 = blockIdx.y * BN;
    const int srow = tid >> 2;                // staging: 64 rows per 256-thread round
    const int skoff = (tid & 3) * 8;          // element offset within BK=32

    f32x4 acc[4][4] = {};

    for (int k0 = 0; k0 < K; k0 += 32) {
        // stage A tile [BM x 32]
#pragma unroll
        for (int c = 0; c < BM / 64; c++) {
            int r = c * 64 + srow;
            int gr = m0 + r;
            const bf16* p;
            if (CAT) {
                int gk = k0 + skoff;
                p = (gk < 256) ? (A1 + (size_t)(gr & rowmask) * 256 + gk)
                               : (A2 + (size_t)gr * 256 + (gk - 256));
            } else {
                p = A1 + (size_t)gr * K + k0 + skoff;
            }
            *(s16x8*)&As[r * 32 + skoff] = *(const s16x8*)p;
        }
        // stage B tile [BN x 32] from BT[Nn,K]
#pragma unroll
        for (int c = 0; c < BN / 64; c++) {
            int r = c * 64 + srow;
            *(s16x8*)&Bs[r * 32 + skoff] =
                *(const s16x8*)(BT + (size_t)(n0 + r) * K + k0 + skoff);
        }
        __syncthreads();
        s16x8 af[4], bf[4];
#pragma unroll
        for (int mi = 0; mi < 4; mi++)
            af[mi] = *(s16x8*)&As[(wr * 64 + mi * 16 + (lane & 15)) * 32 + (lane >> 4) * 8];
#pragma unroll
        for (int ni = 0; ni < 4; ni++)
            bf[ni] = *(s16x8*)&Bs[(wc * 64 + ni * 16 + (lane & 15)) * 32 + (lane >> 4) * 8];
#pragma unroll
        for (int mi = 0; mi < 4; mi++)
#pragma unroll
            for (int ni = 0; ni < 4; ni++)
                acc[mi][ni] = __builtin_amdgcn_mfma_f32_16x16x32_bf16(
                    af[mi], bf[ni], acc[mi][ni], 0, 0, 0);
        __syncthreads();
    }

    if (EPI == E_SILU) {
#pragma unroll
        for (int mi = 0; mi < 4; mi++)
#pragma unroll
            for (int ni = 0; ni < 4; ni++)
#pragma unroll
                for (int r = 0; r < 4; r++) {
                    int row = m0 + wr * 64 + mi * 16 + (lane >> 4) * 4 + r;
                    int col = n0 + wc * 64 + ni * 16 + (lane & 15);
                    float v = acc[mi][ni][r] + bias[col];
                    float s = v / (1.f + __expf(-v));
                    if (col < EE) outB[(size_t)row * EE + col] = f2b(s);
                    else          outB2[(size_t)row * EE + (col - EE)] = f2b(s);
                }
    } else if (EPI == E_BF16) {
#pragma unroll
        for (int mi = 0; mi < 4; mi++)
#pragma unroll
            for (int ni = 0; ni < 4; ni++)
#pragma unroll
                for (int r = 0; r < 4; r++) {
                    int row = m0 + wr * 64 + mi * 16 + (lane >> 4) * 4 + r;
                    int col = n0 + wc * 64 + ni * 16 + (lane & 15);
                    outB[(size_t)row * 256 + col] = f2b(acc[mi][ni][r] + bias[col]);
                }
    } else if (EPI == E_OUT) {
#pragma unroll
        for (int mi = 0; mi < 4; mi++)
#pragma unroll
            for (int ni = 0; ni < 4; ni++)
#pragma unroll
                for (int r = 0; r < 4; r++) {
                    int row = m0 + wr * 64 + mi * 16 + (lane >> 4) * 4 + r;
                    int col = n0 + wc * 64 + ni * 16 + (lane & 15);
                    float v = acc[mi][ni][r] + bias[col] + toF(resid[(size_t)row * 256 + col]);
                    int t = row & 63, n = row >> 6;
                    outF[((size_t)t * NN_ + n) * 256 + col] = v;
                }
    } else if (EPI == E_TRI) {
#pragma unroll
        for (int mi = 0; mi < 4; mi++)
#pragma unroll
            for (int ni = 0; ni < 4; ni++)
#pragma unroll
                for (int r = 0; r < 4; r++) {
                    int row = m0 + wid * 64 + mi * 16 + (lane >> 4) * 4 + r;
                    int col = ni * 16 + (lane & 15);
                    if (col < 48) {
                        float v = acc[mi][ni][r] + bias[col];
                        float* dst = (col < 16) ? outF : (col < 32) ? outF2 : outF3;
                        dst[(size_t)row * 16 + (col & 15)] = v;
                    }
                }
    } else {
        // E_LN1 / E_LN2: relu -> Cs, then row LN(s) in-block. BM=64, BN=256, grid.y=1.
#pragma unroll
        for (int mi = 0; mi < 4; mi++)
#pragma unroll
            for (int ni = 0; ni < 4; ni++)
#pragma unroll
                for (int r = 0; r < 4; r++) {
                    int rl = mi * 16 + (lane >> 4) * 4 + r;
                    int cl = wc * 64 + ni * 16 + (lane & 15);
                    Cs[rl * 260 + cl] = fmaxf(acc[mi][ni][r] + bias[cl], 0.f);
                }
        __syncthreads();
        float g1v[4], b1v[4], g2v[4], b2v[4];
#pragma unroll
        for (int i = 0; i < 4; i++) {
            g1v[i] = g1[lane * 4 + i];
            b1v[i] = b1[lane * 4 + i];
            if (EPI == E_LN2) { g2v[i] = g2[lane * 4 + i]; b2v[i] = b2[lane * 4 + i]; }
        }
        for (int rr = 0; rr < 16; rr++) {
            int rl = wid * 16 + rr;
            int grow = m0 + rl;
            float x[4];
#pragma unroll
            for (int i = 0; i < 4; i++) x[i] = Cs[rl * 260 + lane * 4 + i];
            float s = x[0] + x[1] + x[2] + x[3];
#pragma unroll
            for (int o = 1; o < 64; o <<= 1) s += __shfl_xor(s, o, 64);
            float mu = s * (1.f / 256.f);
            float d[4], ss = 0.f;
#pragma unroll
            for (int i = 0; i < 4; i++) { d[i] = x[i] - mu; ss = fmaf(d[i], d[i], ss); }
#pragma unroll
            for (int o = 1; o < 64; o <<= 1) ss += __shfl_xor(ss, o, 64);
            float inv = rsqrtf(fmaxf(ss * (1.f / 256.f), 0.f) + 1e-5f);
            float y[4];
#pragma unroll
            for (int i = 0; i < 4; i++) y[i] = d[i] * inv * g1v[i] + b1v[i];
            if (EPI == E_LN1) {
                __align__(8) bf16 pk[4];
#pragma unroll
                for (int i = 0; i < 4; i++) pk[i] = f2b(y[i]);
                *(s16x4*)&outB[(size_t)grow * 256 + lane * 4] = *(s16x4*)pk;
            } else {
                // input rows grow = t*1024+n; transposed row = n*64+t for [N,T,H]
                int trow = (grow & 1023) * 64 + (grow >> 10);
                __align__(8) bf16 pk[4];
#pragma unroll
                for (int i = 0; i < 4; i++) pk[i] = f2b(y[i]);
                *(s16x4*)&outB[(size_t)trow * 256 + lane * 4] = *(s16x4*)pk;
                // LN2 on f32 y -> xn, ALSO stored at trow ([N,T] order) so the
                // whole Mamba branch (u/sg/d1/Bm/Cm/yg) is [N,T]-ordered as
                // scan_k and E_OUT expect.  (R5 bug: was written at grow.)
                float s2 = y[0] + y[1] + y[2] + y[3];
#pragma unroll
                for (int o = 1; o < 64; o <<= 1) s2 += __shfl_xor(s2, o, 64);
                float mu2 = s2 * (1.f / 256.f);
                float d2[4], ss2 = 0.f;
#pragma unroll
                for (int i = 0; i < 4; i++) { d2[i] = y[i] - mu2; ss2 = fmaf(d2[i], d2[i], ss2); }
#pragma unroll
                for (int o = 1; o < 64; o <<= 1) ss2 += __shfl_xor(ss2, o, 64);
                float inv2 = rsqrtf(fmaxf(ss2 * (1.f / 256.f), 0.f) + 1e-5f);
                __align__(8) bf16 pk2[4];
#pragma unroll
                for (int i = 0; i < 4; i++) pk2[i] = f2b(d2[i] * inv2 * g2v[i] + b2v[i]);
                *(s16x4*)&outB2[(size_t)trow * 256 + lane * 4] = *(s16x4*)pk2;
            }
        }
    }
}

// ---------------- sparse aggregation (ballot over nnz adj) --------------------------
template <bool GATED>
__global__ __launch_bounds__(256) void agg_k(
    const float* __restrict__ adj, const float* __restrict__ gates,
    const void* __restrict__ src_, bf16* __restrict__ out)
{
    int w = blockIdx.x * 4 + (threadIdx.x >> 6);
    int lane = threadIdx.x & 63;
    int t = w >> 10, n = w & 1023;
    const float* adjrow = adj + ((size_t)t * NN_ + n) * NN_;
    const float* srcF = (const float*)src_;
    const bf16* srcB = (const bf16*)src_;
    float a0 = 0.f, a1 = 0.f, a2 = 0.f, a3 = 0.f;
    for (int ch = 0; ch < 16; ch++) {
        int j0 = ch * 64;
        float av = adjrow[j0 + lane];
        unsigned long long m = __ballot(av != 0.f);
        while (m) {
            int l = __builtin_ctzll(m);
            m &= (m - 1);
            int j = j0 + l;
            float wgt = __shfl(av, l, 64);
            if (GATED) {
                wgt *= gates[(size_t)n * NN_ + j];
                const float* r = srcF + (size_t)j * 256;
                a0 = fmaf(wgt, r[lane], a0);
                a1 = fmaf(wgt, r[lane + 64], a1);
                a2 = fmaf(wgt, r[lane + 128], a2);
                a3 = fmaf(wgt, r[lane + 192], a3);
            } else {
                const bf16* r = srcB + ((size_t)t * NN_ + j) * 256;
                a0 = fmaf(wgt, toF(r[lane]), a0);
                a1 = fmaf(wgt, toF(r[lane + 64]), a1);
                a2 = fmaf(wgt, toF(r[lane + 128]), a2);
                a3 = fmaf(wgt, toF(r[lane + 192]), a3);
            }
        }
    }
    bf16* o = out + ((size_t)t * NN_ + n) * 256;
    o[lane] = f2b(a0);
    o[lane + 64] = f2b(a1);
    o[lane + 128] = f2b(a2);
    o[lane + 192] = f2b(a3);
}

// ---------------- Mamba selective scan ----------------------------------------------
__global__ __launch_bounds__(256) void scan_k(
    const bf16* __restrict__ u, const bf16* __restrict__ sg,
    const float* __restrict__ d1, const float* __restrict__ Bm, const float* __restrict__ Cm,
    const float* __restrict__ Wdt, const float* __restrict__ bdt,
    const float* __restrict__ Alog, const float* __restrict__ D,
    bf16* __restrict__ yg)
{
    int gid = blockIdx.x * 256 + threadIdx.x;
    int n = gid >> 9, e = gid & 511;
    float a[16], wdt[16], h[16];
#pragma unroll
    for (int s = 0; s < 16; s++) {
        a[s] = -__expf(Alog[e * 16 + s]);
        h[s] = 0.f;
    }
#pragma unroll
    for (int k = 0; k < 16; k++) wdt[k] = Wdt[(size_t)k * EE + e];
    float bdte = bdt[e], De = D[e];
    for (int t = 0; t < TT; t++) {
        size_t r = (size_t)n * TT + t;
        float acc = bdte;
#pragma unroll
        for (int k = 0; k < 16; k++) acc = fmaf(d1[r * 16 + k], wdt[k], acc);
        float delta = (acc > 20.f) ? acc : log1pf(__expf(acc));
        float uv = toF(u[r * EE + e]);
        float du = delta * uv;
        float y = 0.f;
#pragma unroll
        for (int s = 0; s < 16; s++) {
            float ad = __expf(delta * a[s]);
            h[s] = fmaf(ad, h[s], du * Bm[r * 16 + s]);
            y = fmaf(Cm[r * 16 + s], h[s], y);
        }
        float o = (y + uv * De) * toF(sg[r * EE + e]);
        yg[r * EE + e] = f2b(o);
    }
}

// ---------------- prep kernels ------------------------------------------------------
__global__ void cast_k(const float* __restrict__ in, bf16* __restrict__ out, int n) {
    int i = blockIdx.x * 256 + threadIdx.x;
    if (i < n) out[i] = f2b(in[i]);
}
// out[Nn][K] = bf16(W[K][Nn])
__global__ void transT_k(const float* __restrict__ W, bf16* __restrict__ out, int K, int Nn) {
    int gid = blockIdx.x * 256 + threadIdx.x;
    if (gid >= K * Nn) return;
    int n = gid / K, k = gid - n * K;
    out[gid] = f2b(W[(size_t)k * Nn + n]);
}
// WdBC^T [64][512]: rows 0-15 Wd, 16-31 WB, 32-47 WC, 48-63 zero; biascat[48]
__global__ void wdbct_k(const float* __restrict__ Wd, const float* __restrict__ WB,
                        const float* __restrict__ WC, bf16* __restrict__ out,
                        const float* __restrict__ bd, const float* __restrict__ bB,
                        const float* __restrict__ bC, float* __restrict__ biascat) {
    int gid = blockIdx.x * 256 + threadIdx.x;
    if (gid < 48) biascat[gid] = (gid < 16) ? bd[gid] : (gid < 32) ? bB[gid - 16] : bC[gid - 32];
    if (gid >= 64 * 512) return;
    int n = gid >> 9, k = gid & 511;
    float v = 0.f;
    if (n < 16)      v = Wd[(size_t)k * 16 + n];
    else if (n < 32) v = WB[(size_t)k * 16 + (n - 16)];
    else if (n < 48) v = WC[(size_t)k * 16 + (n - 32)];
    out[gid] = f2b(v);
}

extern "C" void kernel_launch(void* const* d_in, const int* in_sizes, int n_in,
                              void* d_out, int out_size, void* d_ws, size_t ws_size,
                              hipStream_t stream)
{
    const float* adj   = (const float*)d_in[0];
    const float* pos   = (const float*)d_in[1];
    const float* g1Wm  = (const float*)d_in[2];
    const float* g1bm  = (const float*)d_in[3];
    const float* g1Wq  = (const float*)d_in[4];
    const float* g1Wk  = (const float*)d_in[5];
    const float* g1gb  = (const float*)d_in[6];
    const float* g1Wu  = (const float*)d_in[7];
    const float* g1bu  = (const float*)d_in[8];
    const float* g1lg  = (const float*)d_in[9];
    const float* g1lb  = (const float*)d_in[10];
    const float* g2Wm  = (const float*)d_in[11];
    const float* g2bm  = (const float*)d_in[12];
    const float* g2Wu  = (const float*)d_in[13];
    const float* g2bu  = (const float*)d_in[14];
    const float* g2lg  = (const float*)d_in[15];
    const float* g2lb  = (const float*)d_in[16];
    const float* mlg   = (const float*)d_in[17];
    const float* mlb   = (const float*)d_in[18];
    const float* mWin  = (const float*)d_in[19];
    const float* mbin  = (const float*)d_in[20];
    const float* mWd   = (const float*)d_in[21];
    const float* mbd   = (const float*)d_in[22];
    const float* mWdt  = (const float*)d_in[23];
    const float* mbdt  = (const float*)d_in[24];
    const float* mWB   = (const float*)d_in[25];
    const float* mbB   = (const float*)d_in[26];
    const float* mWC   = (const float*)d_in[27];
    const float* mbC   = (const float*)d_in[28];
    const float* mAlog = (const float*)d_in[29];
    const float* mD    = (const float*)d_in[30];
    const float* mWout = (const float*)d_in[31];
    const float* mbout = (const float*)d_in[32];
    float* out = (float*)d_out;
    char* ws = (char*)d_ws;

    const size_t BIGE = (size_t)TT * NN_ * 256;
    size_t o = 0;
    auto alloc = [&](size_t bytes) { size_t r = o; o += (bytes + 255) & ~(size_t)255; return r; };

    float* msgs  = (float*)(ws + alloc((size_t)NN_ * 256 * 4));
    float* q     = (float*)(ws + alloc((size_t)NN_ * 256 * 4));
    float* kk    = (float*)(ws + alloc((size_t)NN_ * 256 * 4));
    float* gates = (float*)(ws + alloc((size_t)NN_ * NN_ * 4));
    bf16*  Ra    = (bf16*)(ws + alloc(BIGE * 2));                 // agg / msgs2 / xn
    size_t off_x1 = alloc(BIGE * 2);
    bf16*  x1    = (bf16*)(ws + off_x1);
    bf16*  agg2  = (bf16*)(ws + alloc(BIGE * 2));                 // contiguous after x1
    bf16*  x2    = (bf16*)(ws + alloc(BIGE * 2));                 // res, [N,T,H]
    bf16*  yg    = (bf16*)(ws + alloc(BIGE * 2));
    bf16*  sg    = (bf16*)(ws + alloc((size_t)NN_ * TT * EE * 2));
    float* d1    = (float*)(ws + alloc((size_t)NN_ * TT * 16 * 4));
    float* Bm    = (float*)(ws + alloc((size_t)NN_ * TT * 16 * 4));
    float* Cm    = (float*)(ws + alloc((size_t)NN_ * TT * 16 * 4));
    bf16*  u     = (bf16*)(ws + off_x1);                          // aliases x1+agg2
    // transposed bf16 weights
    bf16* posb   = (bf16*)(ws + alloc((size_t)NN_ * 256 * 2));
    bf16* g1WuT  = (bf16*)(ws + alloc((size_t)256 * 512 * 2));
    bf16* g2WmT  = (bf16*)(ws + alloc((size_t)256 * 256 * 2));
    bf16* g2WuT  = (bf16*)(ws + alloc((size_t)256 * 512 * 2));
    bf16* mWinT  = (bf16*)(ws + alloc((size_t)1024 * 256 * 2));
    bf16* mWoutT = (bf16*)(ws + alloc((size_t)256 * 512 * 2));
    bf16* WdBCT  = (bf16*)(ws + alloc((size_t)64 * 512 * 2));
    float* biascat = (float*)(ws + alloc(64 * 4));

    const unsigned ALLR = 0xFFFFFFFFu;
    const int M = TT * NN_;

    // prep: weight transposes + casts
    cast_k<<<NN_, 256, 0, stream>>>(pos, posb, NN_ * 256);
    transT_k<<<(512 * 256 + 255) / 256, 256, 0, stream>>>(g1Wu, g1WuT, 512, 256);
    transT_k<<<(256 * 256 + 255) / 256, 256, 0, stream>>>(g2Wm, g2WmT, 256, 256);
    transT_k<<<(512 * 256 + 255) / 256, 256, 0, stream>>>(g2Wu, g2WuT, 512, 256);
    transT_k<<<(256 * 1024 + 255) / 256, 256, 0, stream>>>(mWin, mWinT, 256, 1024);
    transT_k<<<(512 * 256 + 255) / 256, 256, 0, stream>>>(mWout, mWoutT, 512, 256);
    wdbct_k<<<(64 * 512 + 255) / 256, 256, 0, stream>>>(mWd, mWB, mWC, WdBCT, mbd, mbB, mbC, biascat);

    // S0: msgs = pos @ g1_Wm + bm (f32)
    gemm_k<false, EPI_F32><<<dim3(16, 4), 256, 0, stream>>>(
        pos, g1Wm, msgs, g1bm, nullptr, 1.f, NN_, 256, 256, 256, 256);
    // S1: q, k
    gemm_k<false, EPI_F32><<<dim3(16, 4), 256, 0, stream>>>(
        msgs, g1Wq, q, nullptr, nullptr, 1.f, NN_, 256, 256, 256, 256);
    gemm_k<false, EPI_F32><<<dim3(16, 4), 256, 0, stream>>>(
        msgs, g1Wk, kk, nullptr, nullptr, 1.f, NN_, 256, 256, 256, 256);
    // S2: gates = sigmoid(q @ k^T / 16 + gb)
    gemm_k<true, EPI_SIG_F32><<<dim3(16, 16), 256, 0, stream>>>(
        q, kk, gates, nullptr, g1gb, 1.f / 16.f, NN_, NN_, 256, 256, 256);
    // S3: agg -> Ra
    agg_k<true><<<M / 4, 256, 0, stream>>>(adj, gates, msgs, Ra);
    // S4(+S5): x1 = LN(relu(cat(posb,Ra) @ Wu1 + bu1))
    mfma_k<64, 256, true, E_LN1><<<dim3(1024, 1), 256, 0, stream>>>(
        posb, Ra, 1023u, g1WuT, g1bu, nullptr, nullptr, nullptr, x1, nullptr,
        g1lg, g1lb, nullptr, nullptr, nullptr, M, 512);
    // S6: msgs2 = x1 @ Wm2 + bm2 -> Ra
    mfma_k<64, 256, false, E_BF16><<<dim3(1024, 1), 256, 0, stream>>>(
        x1, x1, ALLR, g2WmT, g2bm, nullptr, nullptr, nullptr, Ra, nullptr,
        nullptr, nullptr, nullptr, nullptr, nullptr, M, 256);
    // S7: agg2 = adj @ msgs2
    agg_k<false><<<M / 4, 256, 0, stream>>>(adj, nullptr, Ra, agg2);
    // S8(+S9+S10): x2 = LN(relu(cat(x1,agg2)@Wu2+bu2)) [transposed], xn = LN2 -> Ra [transposed]
    mfma_k<64, 256, true, E_LN2><<<dim3(1024, 1), 256, 0, stream>>>(
        x1, agg2, ALLR, g2WuT, g2bu, nullptr, nullptr, nullptr, x2, Ra,
        g2lg, g2lb, mlg, mlb, nullptr, M, 512);
    // S11: u/sg = silu halves of xn @ Win + bin   (rows now [N,T] order)
    mfma_k<64, 256, false, E_SILU><<<dim3(1024, 4), 256, 0, stream>>>(
        Ra, Ra, ALLR, mWinT, mbin, nullptr, nullptr, nullptr, u, sg,
        nullptr, nullptr, nullptr, nullptr, nullptr, M, 256);
    // S12 fused: d1 | Bm | Cm = u @ [Wd|WB|WC] + biases
    mfma_k<256, 64, false, E_TRI><<<dim3(256, 1), 256, 0, stream>>>(
        u, u, ALLR, WdBCT, biascat, d1, Bm, Cm, nullptr, nullptr,
        nullptr, nullptr, nullptr, nullptr, nullptr, M, 512);
    // S13: selective scan -> yg
    scan_k<<<NN_ * EE / 256, 256, 0, stream>>>(u, sg, d1, Bm, Cm, mWdt, mbdt, mAlog, mD, yg);
    // S14: out = yg @ Wout + bout + res -> [T,N,H] f32
    mfma_k<64, 256, false, E_OUT><<<dim3(1024, 1), 256, 0, stream>>>(
        yg, yg, ALLR, mWoutT, mbout, out, nullptr, nullptr, nullptr, nullptr,
        nullptr, nullptr, nullptr, nullptr, x2, M, 512);

    (void)in_sizes; (void)n_in; (void)out_size; (void)ws_size;
}

// Round 7
// 1314.528 us; speedup vs baseline: 2.6243x; 1.1996x over previous
//
#include <hip/hip_runtime.h>
#include <hip/hip_bf16.h>

typedef __hip_bfloat16 bf16;
typedef __attribute__((ext_vector_type(8))) short s16x8;
typedef __attribute__((ext_vector_type(4))) short s16x4;
typedef __attribute__((ext_vector_type(4))) float f32x4;

#define TT 64
#define NN_ 1024
#define EE 512

__device__ __forceinline__ float toF(float v) { return v; }
__device__ __forceinline__ float toF(bf16 v) { return __bfloat162float(v); }
__device__ __forceinline__ bf16 f2b(float v) { return __float2bfloat16(v); }

enum { EPI_F32 = 0, EPI_SIG_F32 = 1 };
enum { E_LN1 = 0, E_BF16 = 1, E_LN2 = 2, E_SILU = 3, E_OUT = 4, E_TRI = 5, E_BF16T = 6 };

// ---------------- small fp32 tiled GEMM (S0-S2 only; 1024-row problems) -------------
template <bool TRANSB, int EPI>
__global__ __launch_bounds__(256) void gemm_k(
    const float* __restrict__ A, const float* __restrict__ B,
    float* __restrict__ outF, const float* __restrict__ bias,
    const float* __restrict__ sbeta, float alpha,
    int M, int Nn, int K, int lda, int ldb)
{
    __shared__ float As[16][68];
    __shared__ float Bs[16][68];
    const int tid = threadIdx.x;
    const int tx = tid & 15, ty = tid >> 4;
    const int m0 = blockIdx.x * 64, n0 = blockIdx.y * 64;
    float acc[4][4] = {};

    for (int k0 = 0; k0 < K; k0 += 16) {
        {
            int row = tid >> 2, kk0 = (tid & 3) * 4, grow = m0 + row;
#pragma unroll
            for (int j = 0; j < 4; j++) {
                int kk = kk0 + j, gk = k0 + kk;
                As[kk][row] = (grow < M) ? A[(size_t)grow * lda + gk] : 0.f;
            }
        }
        if (!TRANSB) {
            int kk = tid >> 4, c0 = (tid & 15) * 4;
#pragma unroll
            for (int j = 0; j < 4; j++) {
                int col = c0 + j, gn = n0 + col;
                Bs[kk][col] = (gn < Nn) ? B[(size_t)(k0 + kk) * ldb + gn] : 0.f;
            }
        } else {
            int col = tid >> 2, kk0 = (tid & 3) * 4, gn = n0 + col;
#pragma unroll
            for (int j = 0; j < 4; j++) {
                int kk = kk0 + j;
                Bs[kk][col] = (gn < Nn) ? B[(size_t)gn * ldb + (k0 + kk)] : 0.f;
            }
        }
        __syncthreads();
#pragma unroll
        for (int kk = 0; kk < 16; kk++) {
            float a[4], b[4];
#pragma unroll
            for (int i = 0; i < 4; i++) a[i] = As[kk][ty * 4 + i];
#pragma unroll
            for (int j = 0; j < 4; j++) b[j] = Bs[kk][tx * 4 + j];
#pragma unroll
            for (int i = 0; i < 4; i++)
#pragma unroll
                for (int j = 0; j < 4; j++)
                    acc[i][j] = fmaf(a[i], b[j], acc[i][j]);
        }
        __syncthreads();
    }

    float gb = (EPI == EPI_SIG_F32 && sbeta) ? sbeta[0] : 0.f;
#pragma unroll
    for (int i = 0; i < 4; i++) {
        int row = m0 + ty * 4 + i;
        if (row >= M) continue;
#pragma unroll
        for (int j = 0; j < 4; j++) {
            int col = n0 + tx * 4 + j;
            if (col >= Nn) continue;
            float v = acc[i][j];
            if (EPI == EPI_F32) {
                if (bias) v += bias[col];
                outF[(size_t)row * Nn + col] = v;
            } else {
                v = v * alpha + gb;
                outF[(size_t)row * Nn + col] = 1.f / (1.f + __expf(-v));
            }
        }
    }
}

// ---------------- MFMA bf16 GEMM -----------------------------------------------------
// C[M,Nn] = A[M,K](bf16) @ BT[Nn,K]^T(bf16), fp32 accum, fused epilogues.
// 256 threads = 4 waves. BK=32. BN=256: waves side-by-side; BM=256/BN=64: stacked.
// CAT: A row r = [A1[(r&rowmask),0:256] | A2[r,0:256]], K=512.
template <int BM, int BN, bool CAT, int EPI>
__global__ __launch_bounds__(256) void mfma_k(
    const bf16* __restrict__ A1, const bf16* __restrict__ A2, unsigned rowmask,
    const bf16* __restrict__ BT, const float* __restrict__ bias,
    float* __restrict__ outF, float* __restrict__ outF2, float* __restrict__ outF3,
    bf16* __restrict__ outB, bf16* __restrict__ outB2,
    const float* __restrict__ g1, const float* __restrict__ b1,
    const float* __restrict__ g2, const float* __restrict__ b2,
    const bf16* __restrict__ resid,
    int M, int K)
{
    constexpr bool LN = (EPI == E_LN1 || EPI == E_LN2);
    constexpr int STAGE_B = (BM * 32 + BN * 32) * 2;
    constexpr int SB = LN ? (64 * 260 * 4) : STAGE_B;
    __shared__ __align__(16) char smem[SB];
    short* As = (short*)smem;
    short* Bs = As + BM * 32;
    float* Cs = (float*)smem;   // LN epilogue reuses staging LDS

    const int tid = threadIdx.x;
    const int wid = tid >> 6, lane = tid & 63;
    const int wr = (BN == 256) ? 0 : wid;
    const int wc = (BN == 256) ? wid : 0;
    const int m0 = blockIdx.x * BM, n0 = blockIdx.y * BN;
    const int srow = tid >> 2;
    const int skoff = (tid & 3) * 8;

    f32x4 acc[4][4] = {};

    for (int k0 = 0; k0 < K; k0 += 32) {
#pragma unroll
        for (int c = 0; c < BM / 64; c++) {
            int r = c * 64 + srow;
            int gr = m0 + r;
            const bf16* p;
            if (CAT) {
                int gk = k0 + skoff;
                p = (gk < 256) ? (A1 + (size_t)(gr & rowmask) * 256 + gk)
                               : (A2 + (size_t)gr * 256 + (gk - 256));
            } else {
                p = A1 + (size_t)gr * K + k0 + skoff;
            }
            *(s16x8*)&As[r * 32 + skoff] = *(const s16x8*)p;
        }
#pragma unroll
        for (int c = 0; c < BN / 64; c++) {
            int r = c * 64 + srow;
            *(s16x8*)&Bs[r * 32 + skoff] =
                *(const s16x8*)(BT + (size_t)(n0 + r) * K + k0 + skoff);
        }
        __syncthreads();
        s16x8 af[4], bf[4];
#pragma unroll
        for (int mi = 0; mi < 4; mi++)
            af[mi] = *(s16x8*)&As[(wr * 64 + mi * 16 + (lane & 15)) * 32 + (lane >> 4) * 8];
#pragma unroll
        for (int ni = 0; ni < 4; ni++)
            bf[ni] = *(s16x8*)&Bs[(wc * 64 + ni * 16 + (lane & 15)) * 32 + (lane >> 4) * 8];
#pragma unroll
        for (int mi = 0; mi < 4; mi++)
#pragma unroll
            for (int ni = 0; ni < 4; ni++)
                acc[mi][ni] = __builtin_amdgcn_mfma_f32_16x16x32_bf16(
                    af[mi], bf[ni], acc[mi][ni], 0, 0, 0);
        __syncthreads();
    }

    if (EPI == E_SILU) {
#pragma unroll
        for (int mi = 0; mi < 4; mi++)
#pragma unroll
            for (int ni = 0; ni < 4; ni++)
#pragma unroll
                for (int r = 0; r < 4; r++) {
                    int row = m0 + wr * 64 + mi * 16 + (lane >> 4) * 4 + r;
                    int col = n0 + wc * 64 + ni * 16 + (lane & 15);
                    float v = acc[mi][ni][r] + bias[col];
                    float s = v / (1.f + __expf(-v));
                    if (col < EE) outB[(size_t)row * EE + col] = f2b(s);
                    else          outB2[(size_t)row * EE + (col - EE)] = f2b(s);
                }
    } else if (EPI == E_BF16) {
#pragma unroll
        for (int mi = 0; mi < 4; mi++)
#pragma unroll
            for (int ni = 0; ni < 4; ni++)
#pragma unroll
                for (int r = 0; r < 4; r++) {
                    int row = m0 + wr * 64 + mi * 16 + (lane >> 4) * 4 + r;
                    int col = n0 + wc * 64 + ni * 16 + (lane & 15);
                    outB[(size_t)row * 256 + col] = f2b(acc[mi][ni][r] + bias[col]);
                }
    } else if (EPI == E_BF16T) {
        // rows r = t*1024+j -> store transposed [t][col][j] (for per-t GEMM B^T)
#pragma unroll
        for (int mi = 0; mi < 4; mi++)
#pragma unroll
            for (int ni = 0; ni < 4; ni++)
#pragma unroll
                for (int r = 0; r < 4; r++) {
                    int row = m0 + wr * 64 + mi * 16 + (lane >> 4) * 4 + r;
                    int col = n0 + wc * 64 + ni * 16 + (lane & 15);
                    size_t dst = (((size_t)(row >> 10)) * 256 + col) * 1024 + (row & 1023);
                    outB[dst] = f2b(acc[mi][ni][r] + bias[col]);
                }
    } else if (EPI == E_OUT) {
#pragma unroll
        for (int mi = 0; mi < 4; mi++)
#pragma unroll
            for (int ni = 0; ni < 4; ni++)
#pragma unroll
                for (int r = 0; r < 4; r++) {
                    int row = m0 + wr * 64 + mi * 16 + (lane >> 4) * 4 + r;
                    int col = n0 + wc * 64 + ni * 16 + (lane & 15);
                    float v = acc[mi][ni][r] + bias[col] + toF(resid[(size_t)row * 256 + col]);
                    int t = row & 63, n = row >> 6;
                    outF[((size_t)t * NN_ + n) * 256 + col] = v;
                }
    } else if (EPI == E_TRI) {
#pragma unroll
        for (int mi = 0; mi < 4; mi++)
#pragma unroll
            for (int ni = 0; ni < 4; ni++)
#pragma unroll
                for (int r = 0; r < 4; r++) {
                    int row = m0 + wid * 64 + mi * 16 + (lane >> 4) * 4 + r;
                    int col = ni * 16 + (lane & 15);
                    if (col < 48) {
                        float v = acc[mi][ni][r] + bias[col];
                        float* dst = (col < 16) ? outF : (col < 32) ? outF2 : outF3;
                        dst[(size_t)row * 16 + (col & 15)] = v;
                    }
                }
    } else {
        // E_LN1 / E_LN2: relu -> Cs, then row LN(s). BM=64, BN=256, grid.y=1.
#pragma unroll
        for (int mi = 0; mi < 4; mi++)
#pragma unroll
            for (int ni = 0; ni < 4; ni++)
#pragma unroll
                for (int r = 0; r < 4; r++) {
                    int rl = mi * 16 + (lane >> 4) * 4 + r;
                    int cl = wc * 64 + ni * 16 + (lane & 15);
                    Cs[rl * 260 + cl] = fmaxf(acc[mi][ni][r] + bias[cl], 0.f);
                }
        __syncthreads();
        float g1v[4], b1v[4], g2v[4], b2v[4];
#pragma unroll
        for (int i = 0; i < 4; i++) {
            g1v[i] = g1[lane * 4 + i];
            b1v[i] = b1[lane * 4 + i];
            if (EPI == E_LN2) { g2v[i] = g2[lane * 4 + i]; b2v[i] = b2[lane * 4 + i]; }
        }
        for (int rr = 0; rr < 16; rr++) {
            int rl = wid * 16 + rr;
            int grow = m0 + rl;
            float x[4];
#pragma unroll
            for (int i = 0; i < 4; i++) x[i] = Cs[rl * 260 + lane * 4 + i];
            float s = x[0] + x[1] + x[2] + x[3];
#pragma unroll
            for (int o = 1; o < 64; o <<= 1) s += __shfl_xor(s, o, 64);
            float mu = s * (1.f / 256.f);
            float d[4], ss = 0.f;
#pragma unroll
            for (int i = 0; i < 4; i++) { d[i] = x[i] - mu; ss = fmaf(d[i], d[i], ss); }
#pragma unroll
            for (int o = 1; o < 64; o <<= 1) ss += __shfl_xor(ss, o, 64);
            float inv = rsqrtf(fmaxf(ss * (1.f / 256.f), 0.f) + 1e-5f);
            float y[4];
#pragma unroll
            for (int i = 0; i < 4; i++) y[i] = d[i] * inv * g1v[i] + b1v[i];
            if (EPI == E_LN1) {
                __align__(8) bf16 pk[4];
#pragma unroll
                for (int i = 0; i < 4; i++) pk[i] = f2b(y[i]);
                *(s16x4*)&outB[(size_t)grow * 256 + lane * 4] = *(s16x4*)pk;
            } else {
                int trow = (grow & 1023) * 64 + (grow >> 10);   // [N,T] order
                __align__(8) bf16 pk[4];
#pragma unroll
                for (int i = 0; i < 4; i++) pk[i] = f2b(y[i]);
                *(s16x4*)&outB[(size_t)trow * 256 + lane * 4] = *(s16x4*)pk;
                float s2 = y[0] + y[1] + y[2] + y[3];
#pragma unroll
                for (int o = 1; o < 64; o <<= 1) s2 += __shfl_xor(s2, o, 64);
                float mu2 = s2 * (1.f / 256.f);
                float d2[4], ss2 = 0.f;
#pragma unroll
                for (int i = 0; i < 4; i++) { d2[i] = y[i] - mu2; ss2 = fmaf(d2[i], d2[i], ss2); }
#pragma unroll
                for (int o = 1; o < 64; o <<= 1) ss2 += __shfl_xor(ss2, o, 64);
                float inv2 = rsqrtf(fmaxf(ss2 * (1.f / 256.f), 0.f) + 1e-5f);
                __align__(8) bf16 pk2[4];
#pragma unroll
                for (int i = 0; i < 4; i++) pk2[i] = f2b(d2[i] * inv2 * g2v[i] + b2v[i]);
                *(s16x4*)&outB2[(size_t)trow * 256 + lane * 4] = *(s16x4*)pk2;
            }
        }
    }
}

// ---------------- dense MFMA aggregation (adj is binary -> exact in bf16) -----------
// GATED  (agg1): block = n.  C[64t x 256c] = adj[t, n, j] @ (gates[n,j]*msgs[j,c])
//                A row r=t, stride N*N;  B^T = msgsT[c][j] scaled by gates[n,j].
// !GATED (agg2): block = t*16+nb. C[64n x 256c] = adj[t, n, j] @ msgs2[t][j,c]
//                A row r=n (stride N);  B^T = msgs2T[t][c][j].
// LDS rows padded to 40 shorts (80 B) to break b128 read bank conflicts.
template <bool GATED>
__global__ __launch_bounds__(256) void aggmm_k(
    const float* __restrict__ adj, const float* __restrict__ gates,
    const bf16* __restrict__ BTsrc, bf16* __restrict__ out)
{
    __shared__ __align__(16) short As[64 * 40];
    __shared__ __align__(16) short Bs[256 * 40];
    const int tid = threadIdx.x;
    const int wid = tid >> 6, lane = tid & 63;
    const int bx = blockIdx.x;
    const int srow = tid >> 2;
    const int skoff = (tid & 3) * 8;
    const size_t NN2 = (size_t)NN_ * NN_;

    size_t abase, astride;
    size_t orow0;
    const bf16* bt;
    if (GATED) {
        abase = (size_t)bx * NN_;           // + t*NN2 + j
        astride = NN2;
        bt = BTsrc;                          // msgsT [256][1024]
        orow0 = 0;                           // orow = rowl*1024 + bx
    } else {
        int t = bx >> 4, n0 = (bx & 15) * 64;
        abase = (size_t)t * NN2 + (size_t)n0 * NN_;
        astride = NN_;
        bt = BTsrc + (size_t)t * 256 * 1024; // msgs2T[t]
        orow0 = (size_t)t * 1024 + n0;       // orow = orow0 + rowl
    }

    f32x4 acc[4][4] = {};

    for (int k0 = 0; k0 < 1024; k0 += 32) {
        // A tile [64 x 32]: adj f32 -> bf16 inline (values are exactly 0/1)
        {
            const float* p = adj + abase + (size_t)srow * astride + (k0 + skoff);
            float4 v0 = *(const float4*)p;
            float4 v1 = *(const float4*)(p + 4);
            bf16* d = (bf16*)&As[srow * 40 + skoff];
            d[0] = f2b(v0.x); d[1] = f2b(v0.y); d[2] = f2b(v0.z); d[3] = f2b(v0.w);
            d[4] = f2b(v1.x); d[5] = f2b(v1.y); d[6] = f2b(v1.z); d[7] = f2b(v1.w);
        }
        // B tile [256 x 32]
        if (GATED) {
            float g[8];
            const float* gp = gates + (size_t)bx * NN_ + (k0 + skoff);
#pragma unroll
            for (int i = 0; i < 8; i++) g[i] = gp[i];
#pragma unroll
            for (int c = 0; c < 4; c++) {
                int r = c * 64 + srow;
                s16x8 mv = *(const s16x8*)(bt + (size_t)r * 1024 + (k0 + skoff));
                bf16* d = (bf16*)&Bs[r * 40 + skoff];
#pragma unroll
                for (int i = 0; i < 8; i++) {
                    union { short s; bf16 b; } u;
                    u.s = mv[i];
                    d[i] = f2b(toF(u.b) * g[i]);
                }
            }
        } else {
#pragma unroll
            for (int c = 0; c < 4; c++) {
                int r = c * 64 + srow;
                *(s16x8*)&Bs[r * 40 + skoff] =
                    *(const s16x8*)(bt + (size_t)r * 1024 + (k0 + skoff));
            }
        }
        __syncthreads();
        s16x8 af[4], bf[4];
#pragma unroll
        for (int mi = 0; mi < 4; mi++)
            af[mi] = *(s16x8*)&As[(mi * 16 + (lane & 15)) * 40 + (lane >> 4) * 8];
#pragma unroll
        for (int ni = 0; ni < 4; ni++)
            bf[ni] = *(s16x8*)&Bs[(wid * 64 + ni * 16 + (lane & 15)) * 40 + (lane >> 4) * 8];
#pragma unroll
        for (int mi = 0; mi < 4; mi++)
#pragma unroll
            for (int ni = 0; ni < 4; ni++)
                acc[mi][ni] = __builtin_amdgcn_mfma_f32_16x16x32_bf16(
                    af[mi], bf[ni], acc[mi][ni], 0, 0, 0);
        __syncthreads();
    }

#pragma unroll
    for (int mi = 0; mi < 4; mi++)
#pragma unroll
        for (int ni = 0; ni < 4; ni++)
#pragma unroll
            for (int r = 0; r < 4; r++) {
                int rowl = mi * 16 + (lane >> 4) * 4 + r;
                int col = wid * 64 + ni * 16 + (lane & 15);
                size_t orow = GATED ? ((size_t)rowl * 1024 + bx) : (orow0 + rowl);
                out[orow * 256 + col] = f2b(acc[mi][ni][r]);
            }
}

// ---------------- Mamba selective scan ----------------------------------------------
__global__ __launch_bounds__(256) void scan_k(
    const bf16* __restrict__ u, const bf16* __restrict__ sg,
    const float* __restrict__ d1, const float* __restrict__ Bm, const float* __restrict__ Cm,
    const float* __restrict__ Wdt, const float* __restrict__ bdt,
    const float* __restrict__ Alog, const float* __restrict__ D,
    bf16* __restrict__ yg)
{
    int gid = blockIdx.x * 256 + threadIdx.x;
    int n = gid >> 9, e = gid & 511;
    float a[16], wdt[16], h[16];
#pragma unroll
    for (int s = 0; s < 16; s++) {
        a[s] = -__expf(Alog[e * 16 + s]);
        h[s] = 0.f;
    }
#pragma unroll
    for (int k = 0; k < 16; k++) wdt[k] = Wdt[(size_t)k * EE + e];
    float bdte = bdt[e], De = D[e];
    for (int t = 0; t < TT; t++) {
        size_t r = (size_t)n * TT + t;
        float acc = bdte;
#pragma unroll
        for (int k = 0; k < 16; k++) acc = fmaf(d1[r * 16 + k], wdt[k], acc);
        float delta = (acc > 20.f) ? acc : log1pf(__expf(acc));
        float uv = toF(u[r * EE + e]);
        float du = delta * uv;
        float y = 0.f;
#pragma unroll
        for (int s = 0; s < 16; s++) {
            float ad = __expf(delta * a[s]);
            h[s] = fmaf(ad, h[s], du * Bm[r * 16 + s]);
            y = fmaf(Cm[r * 16 + s], h[s], y);
        }
        float o = (y + uv * De) * toF(sg[r * EE + e]);
        yg[r * EE + e] = f2b(o);
    }
}

// ---------------- prep kernels ------------------------------------------------------
__global__ void cast_k(const float* __restrict__ in, bf16* __restrict__ out, int n) {
    int i = blockIdx.x * 256 + threadIdx.x;
    if (i < n) out[i] = f2b(in[i]);
}
// out[Nn][K] = bf16(W[K][Nn])
__global__ void transT_k(const float* __restrict__ W, bf16* __restrict__ out, int K, int Nn) {
    int gid = blockIdx.x * 256 + threadIdx.x;
    if (gid >= K * Nn) return;
    int n = gid / K, k = gid - n * K;
    out[gid] = f2b(W[(size_t)k * Nn + n]);
}
// msgsT[c][j] = bf16(msgs[j][c])
__global__ void transmsgs_k(const float* __restrict__ msgs, bf16* __restrict__ msgsT) {
    int gid = blockIdx.x * 256 + threadIdx.x;   // 256*1024
    int c = gid >> 10, j = gid & 1023;
    msgsT[gid] = f2b(msgs[(size_t)j * 256 + c]);
}
// WdBC^T [64][512]: rows 0-15 Wd, 16-31 WB, 32-47 WC, 48-63 zero; biascat[48]
__global__ void wdbct_k(const float* __restrict__ Wd, const float* __restrict__ WB,
                        const float* __restrict__ WC, bf16* __restrict__ out,
                        const float* __restrict__ bd, const float* __restrict__ bB,
                        const float* __restrict__ bC, float* __restrict__ biascat) {
    int gid = blockIdx.x * 256 + threadIdx.x;
    if (gid < 48) biascat[gid] = (gid < 16) ? bd[gid] : (gid < 32) ? bB[gid - 16] : bC[gid - 32];
    if (gid >= 64 * 512) return;
    int n = gid >> 9, k = gid & 511;
    float v = 0.f;
    if (n < 16)      v = Wd[(size_t)k * 16 + n];
    else if (n < 32) v = WB[(size_t)k * 16 + (n - 16)];
    else if (n < 48) v = WC[(size_t)k * 16 + (n - 32)];
    out[gid] = f2b(v);
}

extern "C" void kernel_launch(void* const* d_in, const int* in_sizes, int n_in,
                              void* d_out, int out_size, void* d_ws, size_t ws_size,
                              hipStream_t stream)
{
    const float* adj   = (const float*)d_in[0];
    const float* pos   = (const float*)d_in[1];
    const float* g1Wm  = (const float*)d_in[2];
    const float* g1bm  = (const float*)d_in[3];
    const float* g1Wq  = (const float*)d_in[4];
    const float* g1Wk  = (const float*)d_in[5];
    const float* g1gb  = (const float*)d_in[6];
    const float* g1Wu  = (const float*)d_in[7];
    const float* g1bu  = (const float*)d_in[8];
    const float* g1lg  = (const float*)d_in[9];
    const float* g1lb  = (const float*)d_in[10];
    const float* g2Wm  = (const float*)d_in[11];
    const float* g2bm  = (const float*)d_in[12];
    const float* g2Wu  = (const float*)d_in[13];
    const float* g2bu  = (const float*)d_in[14];
    const float* g2lg  = (const float*)d_in[15];
    const float* g2lb  = (const float*)d_in[16];
    const float* mlg   = (const float*)d_in[17];
    const float* mlb   = (const float*)d_in[18];
    const float* mWin  = (const float*)d_in[19];
    const float* mbin  = (const float*)d_in[20];
    const float* mWd   = (const float*)d_in[21];
    const float* mbd   = (const float*)d_in[22];
    const float* mWdt  = (const float*)d_in[23];
    const float* mbdt  = (const float*)d_in[24];
    const float* mWB   = (const float*)d_in[25];
    const float* mbB   = (const float*)d_in[26];
    const float* mWC   = (const float*)d_in[27];
    const float* mbC   = (const float*)d_in[28];
    const float* mAlog = (const float*)d_in[29];
    const float* mD    = (const float*)d_in[30];
    const float* mWout = (const float*)d_in[31];
    const float* mbout = (const float*)d_in[32];
    float* out = (float*)d_out;
    char* ws = (char*)d_ws;

    const size_t BIGE = (size_t)TT * NN_ * 256;
    size_t o = 0;
    auto alloc = [&](size_t bytes) { size_t r = o; o += (bytes + 255) & ~(size_t)255; return r; };

    float* msgs  = (float*)(ws + alloc((size_t)NN_ * 256 * 4));
    float* q     = (float*)(ws + alloc((size_t)NN_ * 256 * 4));
    float* kk    = (float*)(ws + alloc((size_t)NN_ * 256 * 4));
    float* gates = (float*)(ws + alloc((size_t)NN_ * NN_ * 4));
    bf16*  Ra    = (bf16*)(ws + alloc(BIGE * 2));                 // agg / xn
    size_t off_x1 = alloc(BIGE * 2);
    bf16*  x1    = (bf16*)(ws + off_x1);
    bf16*  agg2  = (bf16*)(ws + alloc(BIGE * 2));                 // contiguous after x1
    bf16*  x2    = (bf16*)(ws + alloc(BIGE * 2));                 // res, [N,T,H]
    bf16*  yg    = (bf16*)(ws + alloc(BIGE * 2));
    bf16*  sg    = (bf16*)(ws + alloc((size_t)NN_ * TT * EE * 2));
    float* d1    = (float*)(ws + alloc((size_t)NN_ * TT * 16 * 4));
    float* Bm    = (float*)(ws + alloc((size_t)NN_ * TT * 16 * 4));
    float* Cm    = (float*)(ws + alloc((size_t)NN_ * TT * 16 * 4));
    bf16*  u     = (bf16*)(ws + off_x1);                          // aliases x1+agg2
    // transposed bf16 weights / staging
    bf16* posb   = (bf16*)(ws + alloc((size_t)NN_ * 256 * 2));
    bf16* g1WuT  = (bf16*)(ws + alloc((size_t)256 * 512 * 2));
    bf16* g2WmT  = (bf16*)(ws + alloc((size_t)256 * 256 * 2));
    bf16* g2WuT  = (bf16*)(ws + alloc((size_t)256 * 512 * 2));
    bf16* mWinT  = (bf16*)(ws + alloc((size_t)1024 * 256 * 2));
    bf16* mWoutT = (bf16*)(ws + alloc((size_t)256 * 512 * 2));
    bf16* WdBCT  = (bf16*)(ws + alloc((size_t)64 * 512 * 2));
    float* biascat = (float*)(ws + alloc(64 * 4));
    bf16* msgsT  = (bf16*)(ws + alloc((size_t)256 * 1024 * 2));   // msgs^T bf16
    bf16* msgs2T = (bf16*)(ws + alloc(BIGE * 2));                 // msgs2 [t][c][j]

    const unsigned ALLR = 0xFFFFFFFFu;
    const int M = TT * NN_;

    // prep: weight transposes + casts
    cast_k<<<NN_, 256, 0, stream>>>(pos, posb, NN_ * 256);
    transT_k<<<(512 * 256 + 255) / 256, 256, 0, stream>>>(g1Wu, g1WuT, 512, 256);
    transT_k<<<(256 * 256 + 255) / 256, 256, 0, stream>>>(g2Wm, g2WmT, 256, 256);
    transT_k<<<(512 * 256 + 255) / 256, 256, 0, stream>>>(g2Wu, g2WuT, 512, 256);
    transT_k<<<(256 * 1024 + 255) / 256, 256, 0, stream>>>(mWin, mWinT, 256, 1024);
    transT_k<<<(512 * 256 + 255) / 256, 256, 0, stream>>>(mWout, mWoutT, 512, 256);
    wdbct_k<<<(64 * 512 + 255) / 256, 256, 0, stream>>>(mWd, mWB, mWC, WdBCT, mbd, mbB, mbC, biascat);

    // S0: msgs = pos @ g1_Wm + bm (f32)
    gemm_k<false, EPI_F32><<<dim3(16, 4), 256, 0, stream>>>(
        pos, g1Wm, msgs, g1bm, nullptr, 1.f, NN_, 256, 256, 256, 256);
    transmsgs_k<<<1024, 256, 0, stream>>>(msgs, msgsT);
    // S1: q, k
    gemm_k<false, EPI_F32><<<dim3(16, 4), 256, 0, stream>>>(
        msgs, g1Wq, q, nullptr, nullptr, 1.f, NN_, 256, 256, 256, 256);
    gemm_k<false, EPI_F32><<<dim3(16, 4), 256, 0, stream>>>(
        msgs, g1Wk, kk, nullptr, nullptr, 1.f, NN_, 256, 256, 256, 256);
    // S2: gates = sigmoid(q @ k^T / 16 + gb)
    gemm_k<true, EPI_SIG_F32><<<dim3(16, 16), 256, 0, stream>>>(
        q, kk, gates, nullptr, g1gb, 1.f / 16.f, NN_, NN_, 256, 256, 256);
    // S3: agg -> Ra   (dense MFMA: adj binary)
    aggmm_k<true><<<1024, 256, 0, stream>>>(adj, gates, msgsT, Ra);
    // S4(+S5): x1 = LN(relu(cat(posb,Ra) @ Wu1 + bu1))
    mfma_k<64, 256, true, E_LN1><<<dim3(1024, 1), 256, 0, stream>>>(
        posb, Ra, 1023u, g1WuT, g1bu, nullptr, nullptr, nullptr, x1, nullptr,
        g1lg, g1lb, nullptr, nullptr, nullptr, M, 512);
    // S6: msgs2 = x1 @ Wm2 + bm2 -> msgs2T (transposed store [t][c][j])
    mfma_k<64, 256, false, E_BF16T><<<dim3(1024, 1), 256, 0, stream>>>(
        x1, x1, ALLR, g2WmT, g2bm, nullptr, nullptr, nullptr, msgs2T, nullptr,
        nullptr, nullptr, nullptr, nullptr, nullptr, M, 256);
    // S7: agg2 = adj @ msgs2   (dense MFMA per t)
    aggmm_k<false><<<1024, 256, 0, stream>>>(adj, nullptr, msgs2T, agg2);
    // S8(+S9+S10): x2 = LN(relu(cat(x1,agg2)@Wu2+bu2)) [N,T,H], xn = LN2 -> Ra [N,T,H]
    mfma_k<64, 256, true, E_LN2><<<dim3(1024, 1), 256, 0, stream>>>(
        x1, agg2, ALLR, g2WuT, g2bu, nullptr, nullptr, nullptr, x2, Ra,
        g2lg, g2lb, mlg, mlb, nullptr, M, 512);
    // S11: u/sg = silu halves of xn @ Win + bin
    mfma_k<64, 256, false, E_SILU><<<dim3(1024, 4), 256, 0, stream>>>(
        Ra, Ra, ALLR, mWinT, mbin, nullptr, nullptr, nullptr, u, sg,
        nullptr, nullptr, nullptr, nullptr, nullptr, M, 256);
    // S12 fused: d1 | Bm | Cm = u @ [Wd|WB|WC] + biases
    mfma_k<256, 64, false, E_TRI><<<dim3(256, 1), 256, 0, stream>>>(
        u, u, ALLR, WdBCT, biascat, d1, Bm, Cm, nullptr, nullptr,
        nullptr, nullptr, nullptr, nullptr, nullptr, M, 512);
    // S13: selective scan -> yg
    scan_k<<<NN_ * EE / 256, 256, 0, stream>>>(u, sg, d1, Bm, Cm, mWdt, mbdt, mAlog, mD, yg);
    // S14: out = yg @ Wout + bout + res -> [T,N,H] f32
    mfma_k<64, 256, false, E_OUT><<<dim3(1024, 1), 256, 0, stream>>>(
        yg, yg, ALLR, mWoutT, mbout, out, nullptr, nullptr, nullptr, nullptr,
        nullptr, nullptr, nullptr, nullptr, x2, M, 512);

    (void)in_sizes; (void)n_in; (void)out_size; (void)ws_size;
}

// Round 8
// 1234.550 us; speedup vs baseline: 2.7943x; 1.0648x over previous
//
#include <hip/hip_runtime.h>
#include <hip/hip_bf16.h>

typedef __hip_bfloat16 bf16;
typedef __attribute__((ext_vector_type(8))) short s16x8;
typedef __attribute__((ext_vector_type(4))) short s16x4;
typedef __attribute__((ext_vector_type(4))) float f32x4;

#define TT 64
#define NN_ 1024
#define EE 512

__device__ __forceinline__ float toF(float v) { return v; }
__device__ __forceinline__ float toF(bf16 v) { return __bfloat162float(v); }
__device__ __forceinline__ bf16 f2b(float v) { return __float2bfloat16(v); }

enum { EPI_F32 = 0, EPI_SIG_F32 = 1 };
enum { E_LN1 = 0, E_BF16 = 1, E_LN2 = 2, E_SILU = 3, E_OUT = 4, E_TRI = 5, E_BF16T = 6 };

// ---------------- small fp32 tiled GEMM (S0-S2 only; 1024-row problems) -------------
template <bool TRANSB, int EPI>
__global__ __launch_bounds__(256) void gemm_k(
    const float* __restrict__ A, const float* __restrict__ B,
    float* __restrict__ outF, const float* __restrict__ bias,
    const float* __restrict__ sbeta, float alpha,
    int M, int Nn, int K, int lda, int ldb)
{
    __shared__ float As[16][68];
    __shared__ float Bs[16][68];
    const int tid = threadIdx.x;
    const int tx = tid & 15, ty = tid >> 4;
    const int m0 = blockIdx.x * 64, n0 = blockIdx.y * 64;
    float acc[4][4] = {};

    for (int k0 = 0; k0 < K; k0 += 16) {
        {
            int row = tid >> 2, kk0 = (tid & 3) * 4, grow = m0 + row;
#pragma unroll
            for (int j = 0; j < 4; j++) {
                int kk = kk0 + j, gk = k0 + kk;
                As[kk][row] = (grow < M) ? A[(size_t)grow * lda + gk] : 0.f;
            }
        }
        if (!TRANSB) {
            int kk = tid >> 4, c0 = (tid & 15) * 4;
#pragma unroll
            for (int j = 0; j < 4; j++) {
                int col = c0 + j, gn = n0 + col;
                Bs[kk][col] = (gn < Nn) ? B[(size_t)(k0 + kk) * ldb + gn] : 0.f;
            }
        } else {
            int col = tid >> 2, kk0 = (tid & 3) * 4, gn = n0 + col;
#pragma unroll
            for (int j = 0; j < 4; j++) {
                int kk = kk0 + j;
                Bs[kk][col] = (gn < Nn) ? B[(size_t)gn * ldb + (k0 + kk)] : 0.f;
            }
        }
        __syncthreads();
#pragma unroll
        for (int kk = 0; kk < 16; kk++) {
            float a[4], b[4];
#pragma unroll
            for (int i = 0; i < 4; i++) a[i] = As[kk][ty * 4 + i];
#pragma unroll
            for (int j = 0; j < 4; j++) b[j] = Bs[kk][tx * 4 + j];
#pragma unroll
            for (int i = 0; i < 4; i++)
#pragma unroll
                for (int j = 0; j < 4; j++)
                    acc[i][j] = fmaf(a[i], b[j], acc[i][j]);
        }
        __syncthreads();
    }

    float gb = (EPI == EPI_SIG_F32 && sbeta) ? sbeta[0] : 0.f;
#pragma unroll
    for (int i = 0; i < 4; i++) {
        int row = m0 + ty * 4 + i;
        if (row >= M) continue;
#pragma unroll
        for (int j = 0; j < 4; j++) {
            int col = n0 + tx * 4 + j;
            if (col >= Nn) continue;
            float v = acc[i][j];
            if (EPI == EPI_F32) {
                if (bias) v += bias[col];
                outF[(size_t)row * Nn + col] = v;
            } else {
                v = v * alpha + gb;
                outF[(size_t)row * Nn + col] = 1.f / (1.f + __expf(-v));
            }
        }
    }
}

// ---------------- MFMA bf16 GEMM -----------------------------------------------------
// C[M,Nn] = A[M,K](bf16) @ BT[Nn,K]^T(bf16), fp32 accum, fused epilogues.
// 256 threads = 4 waves. BK=32. BN=256: waves side-by-side; BM=256/BN=64: stacked.
// CAT: A row r = [A1[(r&rowmask),0:256] | A2[r,0:256]], K=512.
template <int BM, int BN, bool CAT, int EPI>
__global__ __launch_bounds__(256) void mfma_k(
    const bf16* __restrict__ A1, const bf16* __restrict__ A2, unsigned rowmask,
    const bf16* __restrict__ BT, const float* __restrict__ bias,
    float* __restrict__ outF,
    bf16* __restrict__ outB, bf16* __restrict__ outB2,
    const float* __restrict__ g1, const float* __restrict__ b1,
    const float* __restrict__ g2, const float* __restrict__ b2,
    const bf16* __restrict__ resid,
    int M, int K)
{
    constexpr bool LN = (EPI == E_LN1 || EPI == E_LN2);
    constexpr int STAGE_B = (BM * 32 + BN * 32) * 2;
    constexpr int SB = LN ? (64 * 260 * 4) : STAGE_B;
    __shared__ __align__(16) char smem[SB];
    short* As = (short*)smem;
    short* Bs = As + BM * 32;
    float* Cs = (float*)smem;   // LN epilogue reuses staging LDS

    const int tid = threadIdx.x;
    const int wid = tid >> 6, lane = tid & 63;
    const int wr = (BN == 256) ? 0 : wid;
    const int wc = (BN == 256) ? wid : 0;
    const int m0 = blockIdx.x * BM, n0 = blockIdx.y * BN;
    const int srow = tid >> 2;
    const int skoff = (tid & 3) * 8;

    f32x4 acc[4][4] = {};

    for (int k0 = 0; k0 < K; k0 += 32) {
#pragma unroll
        for (int c = 0; c < BM / 64; c++) {
            int r = c * 64 + srow;
            int gr = m0 + r;
            const bf16* p;
            if (CAT) {
                int gk = k0 + skoff;
                p = (gk < 256) ? (A1 + (size_t)(gr & rowmask) * 256 + gk)
                               : (A2 + (size_t)gr * 256 + (gk - 256));
            } else {
                p = A1 + (size_t)gr * K + k0 + skoff;
            }
            *(s16x8*)&As[r * 32 + skoff] = *(const s16x8*)p;
        }
#pragma unroll
        for (int c = 0; c < BN / 64; c++) {
            int r = c * 64 + srow;
            *(s16x8*)&Bs[r * 32 + skoff] =
                *(const s16x8*)(BT + (size_t)(n0 + r) * K + k0 + skoff);
        }
        __syncthreads();
        s16x8 af[4], bf[4];
#pragma unroll
        for (int mi = 0; mi < 4; mi++)
            af[mi] = *(s16x8*)&As[(wr * 64 + mi * 16 + (lane & 15)) * 32 + (lane >> 4) * 8];
#pragma unroll
        for (int ni = 0; ni < 4; ni++)
            bf[ni] = *(s16x8*)&Bs[(wc * 64 + ni * 16 + (lane & 15)) * 32 + (lane >> 4) * 8];
#pragma unroll
        for (int mi = 0; mi < 4; mi++)
#pragma unroll
            for (int ni = 0; ni < 4; ni++)
                acc[mi][ni] = __builtin_amdgcn_mfma_f32_16x16x32_bf16(
                    af[mi], bf[ni], acc[mi][ni], 0, 0, 0);
        __syncthreads();
    }

    if (EPI == E_SILU) {
#pragma unroll
        for (int mi = 0; mi < 4; mi++)
#pragma unroll
            for (int ni = 0; ni < 4; ni++)
#pragma unroll
                for (int r = 0; r < 4; r++) {
                    int row = m0 + wr * 64 + mi * 16 + (lane >> 4) * 4 + r;
                    int col = n0 + wc * 64 + ni * 16 + (lane & 15);
                    float v = acc[mi][ni][r] + bias[col];
                    float s = v / (1.f + __expf(-v));
                    if (col < EE) outB[(size_t)row * EE + col] = f2b(s);
                    else          outB2[(size_t)row * EE + (col - EE)] = f2b(s);
                }
    } else if (EPI == E_BF16) {
#pragma unroll
        for (int mi = 0; mi < 4; mi++)
#pragma unroll
            for (int ni = 0; ni < 4; ni++)
#pragma unroll
                for (int r = 0; r < 4; r++) {
                    int row = m0 + wr * 64 + mi * 16 + (lane >> 4) * 4 + r;
                    int col = n0 + wc * 64 + ni * 16 + (lane & 15);
                    outB[(size_t)row * 256 + col] = f2b(acc[mi][ni][r] + bias[col]);
                }
    } else if (EPI == E_BF16T) {
        // rows r = t*1024+j -> store transposed [t][col][j]
#pragma unroll
        for (int mi = 0; mi < 4; mi++)
#pragma unroll
            for (int ni = 0; ni < 4; ni++)
#pragma unroll
                for (int r = 0; r < 4; r++) {
                    int row = m0 + wr * 64 + mi * 16 + (lane >> 4) * 4 + r;
                    int col = n0 + wc * 64 + ni * 16 + (lane & 15);
                    size_t dst = (((size_t)(row >> 10)) * 256 + col) * 1024 + (row & 1023);
                    outB[dst] = f2b(acc[mi][ni][r] + bias[col]);
                }
    } else if (EPI == E_OUT) {
#pragma unroll
        for (int mi = 0; mi < 4; mi++)
#pragma unroll
            for (int ni = 0; ni < 4; ni++)
#pragma unroll
                for (int r = 0; r < 4; r++) {
                    int row = m0 + wr * 64 + mi * 16 + (lane >> 4) * 4 + r;
                    int col = n0 + wc * 64 + ni * 16 + (lane & 15);
                    float v = acc[mi][ni][r] + bias[col] + toF(resid[(size_t)row * 256 + col]);
                    int t = row & 63, n = row >> 6;
                    outF[((size_t)t * NN_ + n) * 256 + col] = v;
                }
    } else if (EPI == E_TRI) {
        // dbc[M,48]: cols 0-15 d1, 16-31 Bm, 32-47 Cm
#pragma unroll
        for (int mi = 0; mi < 4; mi++)
#pragma unroll
            for (int ni = 0; ni < 4; ni++)
#pragma unroll
                for (int r = 0; r < 4; r++) {
                    int row = m0 + wid * 64 + mi * 16 + (lane >> 4) * 4 + r;
                    int col = ni * 16 + (lane & 15);
                    if (col < 48) {
                        float v = acc[mi][ni][r] + bias[col];
                        outF[(size_t)row * 48 + col] = v;
                    }
                }
    } else {
        // E_LN1 / E_LN2: relu -> Cs, then row LN(s). BM=64, BN=256, grid.y=1.
#pragma unroll
        for (int mi = 0; mi < 4; mi++)
#pragma unroll
            for (int ni = 0; ni < 4; ni++)
#pragma unroll
                for (int r = 0; r < 4; r++) {
                    int rl = mi * 16 + (lane >> 4) * 4 + r;
                    int cl = wc * 64 + ni * 16 + (lane & 15);
                    Cs[rl * 260 + cl] = fmaxf(acc[mi][ni][r] + bias[cl], 0.f);
                }
        __syncthreads();
        float g1v[4], b1v[4], g2v[4], b2v[4];
#pragma unroll
        for (int i = 0; i < 4; i++) {
            g1v[i] = g1[lane * 4 + i];
            b1v[i] = b1[lane * 4 + i];
            if (EPI == E_LN2) { g2v[i] = g2[lane * 4 + i]; b2v[i] = b2[lane * 4 + i]; }
        }
        for (int rr = 0; rr < 16; rr++) {
            int rl = wid * 16 + rr;
            int grow = m0 + rl;
            float x[4];
#pragma unroll
            for (int i = 0; i < 4; i++) x[i] = Cs[rl * 260 + lane * 4 + i];
            float s = x[0] + x[1] + x[2] + x[3];
#pragma unroll
            for (int o = 1; o < 64; o <<= 1) s += __shfl_xor(s, o, 64);
            float mu = s * (1.f / 256.f);
            float d[4], ss = 0.f;
#pragma unroll
            for (int i = 0; i < 4; i++) { d[i] = x[i] - mu; ss = fmaf(d[i], d[i], ss); }
#pragma unroll
            for (int o = 1; o < 64; o <<= 1) ss += __shfl_xor(ss, o, 64);
            float inv = rsqrtf(fmaxf(ss * (1.f / 256.f), 0.f) + 1e-5f);
            float y[4];
#pragma unroll
            for (int i = 0; i < 4; i++) y[i] = d[i] * inv * g1v[i] + b1v[i];
            if (EPI == E_LN1) {
                __align__(8) bf16 pk[4];
#pragma unroll
                for (int i = 0; i < 4; i++) pk[i] = f2b(y[i]);
                *(s16x4*)&outB[(size_t)grow * 256 + lane * 4] = *(s16x4*)pk;
            } else {
                int trow = (grow & 1023) * 64 + (grow >> 10);   // [N,T] order
                __align__(8) bf16 pk[4];
#pragma unroll
                for (int i = 0; i < 4; i++) pk[i] = f2b(y[i]);
                *(s16x4*)&outB[(size_t)trow * 256 + lane * 4] = *(s16x4*)pk;
                float s2 = y[0] + y[1] + y[2] + y[3];
#pragma unroll
                for (int o = 1; o < 64; o <<= 1) s2 += __shfl_xor(s2, o, 64);
                float mu2 = s2 * (1.f / 256.f);
                float d2[4], ss2 = 0.f;
#pragma unroll
                for (int i = 0; i < 4; i++) { d2[i] = y[i] - mu2; ss2 = fmaf(d2[i], d2[i], ss2); }
#pragma unroll
                for (int o = 1; o < 64; o <<= 1) ss2 += __shfl_xor(ss2, o, 64);
                float inv2 = rsqrtf(fmaxf(ss2 * (1.f / 256.f), 0.f) + 1e-5f);
                __align__(8) bf16 pk2[4];
#pragma unroll
                for (int i = 0; i < 4; i++) pk2[i] = f2b(d2[i] * inv2 * g2v[i] + b2v[i]);
                *(s16x4*)&outB2[(size_t)trow * 256 + lane * 4] = *(s16x4*)pk2;
            }
        }
    }
}

// ---------------- dense MFMA aggregation (adj is binary -> exact in bf16) -----------
template <bool GATED>
__global__ __launch_bounds__(256) void aggmm_k(
    const float* __restrict__ adj, const float* __restrict__ gates,
    const bf16* __restrict__ BTsrc, bf16* __restrict__ out)
{
    __shared__ __align__(16) short As[64 * 40];
    __shared__ __align__(16) short Bs[256 * 40];
    const int tid = threadIdx.x;
    const int wid = tid >> 6, lane = tid & 63;
    const int bx = blockIdx.x;
    const int srow = tid >> 2;
    const int skoff = (tid & 3) * 8;
    const size_t NN2 = (size_t)NN_ * NN_;

    size_t abase, astride;
    size_t orow0;
    const bf16* bt;
    if (GATED) {
        abase = (size_t)bx * NN_;
        astride = NN2;
        bt = BTsrc;
        orow0 = 0;
    } else {
        int t = bx >> 4, n0 = (bx & 15) * 64;
        abase = (size_t)t * NN2 + (size_t)n0 * NN_;
        astride = NN_;
        bt = BTsrc + (size_t)t * 256 * 1024;
        orow0 = (size_t)t * 1024 + n0;
    }

    f32x4 acc[4][4] = {};

    for (int k0 = 0; k0 < 1024; k0 += 32) {
        {
            const float* p = adj + abase + (size_t)srow * astride + (k0 + skoff);
            float4 v0 = *(const float4*)p;
            float4 v1 = *(const float4*)(p + 4);
            bf16* d = (bf16*)&As[srow * 40 + skoff];
            d[0] = f2b(v0.x); d[1] = f2b(v0.y); d[2] = f2b(v0.z); d[3] = f2b(v0.w);
            d[4] = f2b(v1.x); d[5] = f2b(v1.y); d[6] = f2b(v1.z); d[7] = f2b(v1.w);
        }
        if (GATED) {
            float g[8];
            const float* gp = gates + (size_t)bx * NN_ + (k0 + skoff);
#pragma unroll
            for (int i = 0; i < 8; i++) g[i] = gp[i];
#pragma unroll
            for (int c = 0; c < 4; c++) {
                int r = c * 64 + srow;
                s16x8 mv = *(const s16x8*)(bt + (size_t)r * 1024 + (k0 + skoff));
                bf16* d = (bf16*)&Bs[r * 40 + skoff];
#pragma unroll
                for (int i = 0; i < 8; i++) {
                    union { short s; bf16 b; } u;
                    u.s = mv[i];
                    d[i] = f2b(toF(u.b) * g[i]);
                }
            }
        } else {
#pragma unroll
            for (int c = 0; c < 4; c++) {
                int r = c * 64 + srow;
                *(s16x8*)&Bs[r * 40 + skoff] =
                    *(const s16x8*)(bt + (size_t)r * 1024 + (k0 + skoff));
            }
        }
        __syncthreads();
        s16x8 af[4], bf[4];
#pragma unroll
        for (int mi = 0; mi < 4; mi++)
            af[mi] = *(s16x8*)&As[(mi * 16 + (lane & 15)) * 40 + (lane >> 4) * 8];
#pragma unroll
        for (int ni = 0; ni < 4; ni++)
            bf[ni] = *(s16x8*)&Bs[(wid * 64 + ni * 16 + (lane & 15)) * 40 + (lane >> 4) * 8];
#pragma unroll
        for (int mi = 0; mi < 4; mi++)
#pragma unroll
            for (int ni = 0; ni < 4; ni++)
                acc[mi][ni] = __builtin_amdgcn_mfma_f32_16x16x32_bf16(
                    af[mi], bf[ni], acc[mi][ni], 0, 0, 0);
        __syncthreads();
    }

#pragma unroll
    for (int mi = 0; mi < 4; mi++)
#pragma unroll
        for (int ni = 0; ni < 4; ni++)
#pragma unroll
            for (int r = 0; r < 4; r++) {
                int rowl = mi * 16 + (lane >> 4) * 4 + r;
                int col = wid * 64 + ni * 16 + (lane & 15);
                size_t orow = GATED ? ((size_t)rowl * 1024 + bx) : (orow0 + rowl);
                out[orow * 256 + col] = f2b(acc[mi][ni][r]);
            }
}

// ---------------- Mamba selective scan (block = n, thread = e) ----------------------
// dbc[M,48] rows: [d1(16) | Bm(16) | Cm(16)]. n = blockIdx -> dbc addresses are
// wave-uniform -> compiler emits scalar (s_load) reads; u/sg/yg stay coalesced.
__global__ __launch_bounds__(512) void scan_k(
    const bf16* __restrict__ u, const bf16* __restrict__ sg,
    const float* __restrict__ dbc,
    const float* __restrict__ Wdt, const float* __restrict__ bdt,
    const float* __restrict__ Alog, const float* __restrict__ D,
    bf16* __restrict__ yg)
{
    const int n = blockIdx.x, e = threadIdx.x;
    float a[16], wdt[16], h[16];
#pragma unroll
    for (int s = 0; s < 16; s++) {
        a[s] = -__expf(Alog[e * 16 + s]);
        h[s] = 0.f;
    }
#pragma unroll
    for (int k = 0; k < 16; k++) wdt[k] = Wdt[(size_t)k * EE + e];
    const float bdte = bdt[e], De = D[e];
    const float* __restrict__ rowp = dbc + (size_t)n * TT * 48;
    const size_t base = (size_t)n * TT * EE + e;
#pragma unroll 1
    for (int t = 0; t < TT; t++) {
        const float* __restrict__ r = rowp + t * 48;
        float acc = bdte;
#pragma unroll
        for (int k = 0; k < 16; k++) acc = fmaf(r[k], wdt[k], acc);
        float delta = (acc > 20.f) ? acc : __logf(1.f + __expf(acc));
        size_t idx = base + (size_t)t * EE;
        float uv = toF(u[idx]);
        float du = delta * uv;
        float y = 0.f;
#pragma unroll
        for (int s = 0; s < 16; s++) {
            float ad = __expf(delta * a[s]);
            h[s] = fmaf(ad, h[s], du * r[16 + s]);
            y = fmaf(r[32 + s], h[s], y);
        }
        yg[idx] = f2b((y + uv * De) * toF(sg[idx]));
    }
}

// ---------------- prep kernels ------------------------------------------------------
__global__ void cast_k(const float* __restrict__ in, bf16* __restrict__ out, int n) {
    int i = blockIdx.x * 256 + threadIdx.x;
    if (i < n) out[i] = f2b(in[i]);
}
__global__ void transT_k(const float* __restrict__ W, bf16* __restrict__ out, int K, int Nn) {
    int gid = blockIdx.x * 256 + threadIdx.x;
    if (gid >= K * Nn) return;
    int n = gid / K, k = gid - n * K;
    out[gid] = f2b(W[(size_t)k * Nn + n]);
}
__global__ void transmsgs_k(const float* __restrict__ msgs, bf16* __restrict__ msgsT) {
    int gid = blockIdx.x * 256 + threadIdx.x;
    int c = gid >> 10, j = gid & 1023;
    msgsT[gid] = f2b(msgs[(size_t)j * 256 + c]);
}
__global__ void wdbct_k(const float* __restrict__ Wd, const float* __restrict__ WB,
                        const float* __restrict__ WC, bf16* __restrict__ out,
                        const float* __restrict__ bd, const float* __restrict__ bB,
                        const float* __restrict__ bC, float* __restrict__ biascat) {
    int gid = blockIdx.x * 256 + threadIdx.x;
    if (gid < 48) biascat[gid] = (gid < 16) ? bd[gid] : (gid < 32) ? bB[gid - 16] : bC[gid - 32];
    if (gid >= 64 * 512) return;
    int n = gid >> 9, k = gid & 511;
    float v = 0.f;
    if (n < 16)      v = Wd[(size_t)k * 16 + n];
    else if (n < 32) v = WB[(size_t)k * 16 + (n - 16)];
    else if (n < 48) v = WC[(size_t)k * 16 + (n - 32)];
    out[gid] = f2b(v);
}

extern "C" void kernel_launch(void* const* d_in, const int* in_sizes, int n_in,
                              void* d_out, int out_size, void* d_ws, size_t ws_size,
                              hipStream_t stream)
{
    const float* adj   = (const float*)d_in[0];
    const float* pos   = (const float*)d_in[1];
    const float* g1Wm  = (const float*)d_in[2];
    const float* g1bm  = (const float*)d_in[3];
    const float* g1Wq  = (const float*)d_in[4];
    const float* g1Wk  = (const float*)d_in[5];
    const float* g1gb  = (const float*)d_in[6];
    const float* g1Wu  = (const float*)d_in[7];
    const float* g1bu  = (const float*)d_in[8];
    const float* g1lg  = (const float*)d_in[9];
    const float* g1lb  = (const float*)d_in[10];
    const float* g2Wm  = (const float*)d_in[11];
    const float* g2bm  = (const float*)d_in[12];
    const float* g2Wu  = (const float*)d_in[13];
    const float* g2bu  = (const float*)d_in[14];
    const float* g2lg  = (const float*)d_in[15];
    const float* g2lb  = (const float*)d_in[16];
    const float* mlg   = (const float*)d_in[17];
    const float* mlb   = (const float*)d_in[18];
    const float* mWin  = (const float*)d_in[19];
    const float* mbin  = (const float*)d_in[20];
    const float* mWd   = (const float*)d_in[21];
    const float* mbd   = (const float*)d_in[22];
    const float* mWdt  = (const float*)d_in[23];
    const float* mbdt  = (const float*)d_in[24];
    const float* mWB   = (const float*)d_in[25];
    const float* mbB   = (const float*)d_in[26];
    const float* mWC   = (const float*)d_in[27];
    const float* mbC   = (const float*)d_in[28];
    const float* mAlog = (const float*)d_in[29];
    const float* mD    = (const float*)d_in[30];
    const float* mWout = (const float*)d_in[31];
    const float* mbout = (const float*)d_in[32];
    float* out = (float*)d_out;
    char* ws = (char*)d_ws;

    const size_t BIGE = (size_t)TT * NN_ * 256;
    size_t o = 0;
    auto alloc = [&](size_t bytes) { size_t r = o; o += (bytes + 255) & ~(size_t)255; return r; };

    float* msgs  = (float*)(ws + alloc((size_t)NN_ * 256 * 4));
    float* q     = (float*)(ws + alloc((size_t)NN_ * 256 * 4));
    float* kk    = (float*)(ws + alloc((size_t)NN_ * 256 * 4));
    float* gates = (float*)(ws + alloc((size_t)NN_ * NN_ * 4));
    bf16*  Ra    = (bf16*)(ws + alloc(BIGE * 2));                 // agg / xn
    size_t off_x1 = alloc(BIGE * 2);
    bf16*  x1    = (bf16*)(ws + off_x1);
    bf16*  agg2  = (bf16*)(ws + alloc(BIGE * 2));                 // contiguous after x1
    bf16*  x2    = (bf16*)(ws + alloc(BIGE * 2));                 // res, [N,T,H]
    bf16*  yg    = (bf16*)(ws + alloc(BIGE * 2));
    bf16*  sg    = (bf16*)(ws + alloc((size_t)NN_ * TT * EE * 2));
    float* dbc   = (float*)(ws + alloc((size_t)TT * NN_ * 48 * 4));  // [M,48] d1|Bm|Cm
    bf16*  u     = (bf16*)(ws + off_x1);                          // aliases x1+agg2
    // transposed bf16 weights / staging
    bf16* posb   = (bf16*)(ws + alloc((size_t)NN_ * 256 * 2));
    bf16* g1WuT  = (bf16*)(ws + alloc((size_t)256 * 512 * 2));
    bf16* g2WmT  = (bf16*)(ws + alloc((size_t)256 * 256 * 2));
    bf16* g2WuT  = (bf16*)(ws + alloc((size_t)256 * 512 * 2));
    bf16* mWinT  = (bf16*)(ws + alloc((size_t)1024 * 256 * 2));
    bf16* mWoutT = (bf16*)(ws + alloc((size_t)256 * 512 * 2));
    bf16* WdBCT  = (bf16*)(ws + alloc((size_t)64 * 512 * 2));
    float* biascat = (float*)(ws + alloc(64 * 4));
    bf16* msgsT  = (bf16*)(ws + alloc((size_t)256 * 1024 * 2));
    bf16* msgs2T = (bf16*)(ws + alloc(BIGE * 2));

    const unsigned ALLR = 0xFFFFFFFFu;
    const int M = TT * NN_;

    // prep
    cast_k<<<NN_, 256, 0, stream>>>(pos, posb, NN_ * 256);
    transT_k<<<(512 * 256 + 255) / 256, 256, 0, stream>>>(g1Wu, g1WuT, 512, 256);
    transT_k<<<(256 * 256 + 255) / 256, 256, 0, stream>>>(g2Wm, g2WmT, 256, 256);
    transT_k<<<(512 * 256 + 255) / 256, 256, 0, stream>>>(g2Wu, g2WuT, 512, 256);
    transT_k<<<(256 * 1024 + 255) / 256, 256, 0, stream>>>(mWin, mWinT, 256, 1024);
    transT_k<<<(512 * 256 + 255) / 256, 256, 0, stream>>>(mWout, mWoutT, 512, 256);
    wdbct_k<<<(64 * 512 + 255) / 256, 256, 0, stream>>>(mWd, mWB, mWC, WdBCT, mbd, mbB, mbC, biascat);

    // S0: msgs = pos @ g1_Wm + bm (f32)
    gemm_k<false, EPI_F32><<<dim3(16, 4), 256, 0, stream>>>(
        pos, g1Wm, msgs, g1bm, nullptr, 1.f, NN_, 256, 256, 256, 256);
    transmsgs_k<<<1024, 256, 0, stream>>>(msgs, msgsT);
    // S1: q, k
    gemm_k<false, EPI_F32><<<dim3(16, 4), 256, 0, stream>>>(
        msgs, g1Wq, q, nullptr, nullptr, 1.f, NN_, 256, 256, 256, 256);
    gemm_k<false, EPI_F32><<<dim3(16, 4), 256, 0, stream>>>(
        msgs, g1Wk, kk, nullptr, nullptr, 1.f, NN_, 256, 256, 256, 256);
    // S2: gates = sigmoid(q @ k^T / 16 + gb)
    gemm_k<true, EPI_SIG_F32><<<dim3(16, 16), 256, 0, stream>>>(
        q, kk, gates, nullptr, g1gb, 1.f / 16.f, NN_, NN_, 256, 256, 256);
    // S3: agg -> Ra
    aggmm_k<true><<<1024, 256, 0, stream>>>(adj, gates, msgsT, Ra);
    // S4(+S5): x1 = LN(relu(cat(posb,Ra) @ Wu1 + bu1))
    mfma_k<64, 256, true, E_LN1><<<dim3(1024, 1), 256, 0, stream>>>(
        posb, Ra, 1023u, g1WuT, g1bu, nullptr, x1, nullptr,
        g1lg, g1lb, nullptr, nullptr, nullptr, M, 512);
    // S6: msgs2 = x1 @ Wm2 + bm2 -> msgs2T ([t][c][j])
    mfma_k<64, 256, false, E_BF16T><<<dim3(1024, 1), 256, 0, stream>>>(
        x1, x1, ALLR, g2WmT, g2bm, nullptr, msgs2T, nullptr,
        nullptr, nullptr, nullptr, nullptr, nullptr, M, 256);
    // S7: agg2 = adj @ msgs2
    aggmm_k<false><<<1024, 256, 0, stream>>>(adj, nullptr, msgs2T, agg2);
    // S8(+S9+S10): x2 = LN(relu(cat(x1,agg2)@Wu2+bu2)) [N,T,H], xn = LN2 -> Ra [N,T,H]
    mfma_k<64, 256, true, E_LN2><<<dim3(1024, 1), 256, 0, stream>>>(
        x1, agg2, ALLR, g2WuT, g2bu, nullptr, x2, Ra,
        g2lg, g2lb, mlg, mlb, nullptr, M, 512);
    // S11: u/sg = silu halves of xn @ Win + bin
    mfma_k<64, 256, false, E_SILU><<<dim3(1024, 4), 256, 0, stream>>>(
        Ra, Ra, ALLR, mWinT, mbin, nullptr, u, sg,
        nullptr, nullptr, nullptr, nullptr, nullptr, M, 256);
    // S12 fused: dbc = u @ [Wd|WB|WC] + biases  ([M,48] interleaved)
    mfma_k<256, 64, false, E_TRI><<<dim3(256, 1), 256, 0, stream>>>(
        u, u, ALLR, WdBCT, biascat, dbc, nullptr, nullptr,
        nullptr, nullptr, nullptr, nullptr, nullptr, M, 512);
    // S13: selective scan -> yg  (block per n, thread per e)
    scan_k<<<NN_, 512, 0, stream>>>(u, sg, dbc, mWdt, mbdt, mAlog, mD, yg);
    // S14: out = yg @ Wout + bout + res -> [T,N,H] f32
    mfma_k<64, 256, false, E_OUT><<<dim3(1024, 1), 256, 0, stream>>>(
        yg, yg, ALLR, mWoutT, mbout, out, nullptr, nullptr,
        nullptr, nullptr, nullptr, nullptr, x2, M, 512);

    (void)in_sizes; (void)n_in; (void)out_size; (void)ws_size;
}